// Round 5
// baseline (22828.101 us; speedup 1.0000x reference)
//
#include <hip/hip_runtime.h>

// ---- problem dims ----
#define Bn   256
#define Tn   512
#define Fn   5
#define Hn   512
#define BBn  128
#define KSn  544          // 512 (H) + 5 (x) + pad to 17*32
#define KSP  552          // LDS row stride (shorts) for 544-col tiles: +8 -> 2-way banks only
#define BBP  136          // LDS row stride (shorts) for 128-col tiles
#define NC   8            // clusters (XCD round-robin by blockIdx%8 — verified at runtime, not assumed)
#define WPC  32           // workgroups per cluster
#define NWG  (NC*WPC)

typedef __attribute__((ext_vector_type(8))) short bf16x8;
typedef __attribute__((ext_vector_type(4))) float f32x4;

// ---- d_ws layout (bytes) ----
#define WS_BAR   0                        // per-cluster main counters, 128B apart (8 x 128B)
#define WS_PRB   1024                     // per-cluster probe counters, 128B apart
#define WS_DC    2048                     // device-wide startup barrier counter
#define WS_XCC   4096                     // per-WG XCC id table (256 ints)
#define WS_POK   5120                     // per-WG probe-ok table (256 ints)
#define WS_PDT   6144                     // per-WG probe data slots (256 x 64B)
#define WS_H     24576                    // h_shared [Bn][KSn] bf16 (cols 512..516 = x_t, rest 0)
#define WS_HL    (WS_H   + Bn*KSn*2)      // hlstm    [Bn][KSn] bf16
#define WS_FEAT  (WS_HL  + Bn*KSn*2)      // feat     [Bn][BBn] bf16
#define WS_WH    (WS_FEAT + Bn*BBn*2)     // Wh_ext   [2048][KSn] bf16 (k>=512 -> Wi, pad 0)
#define WS_BB    (WS_WH  + 2048*KSn*2)    // bb_ext   [128][KSn] bf16
#define WS_FF    (WS_BB  + 128*KSn*2)     // ff       [4][Hn][BBn] bf16

// ---- dynamic LDS layout (bytes) ----
#define LB_A     0                        // activation stage: 32*KSP*2 = 35328 (reused: h / hlstm / feat)
#define LB_WH    (LB_A + 32*KSP*2)        // Wh slice: [4 gates][16 cols][KSP] = 70656
#define LB_FF    (LB_WH + 64*KSP*2)       // ff slice: [4 mats][16 cols][BBP] = 17408
#define DYN_LDS  (LB_FF + 64*BBP*2)       // = 123392 B (+9216 static lbuf = 132608 <= 160K)

// ---- d_out layout (floats) ----
#define YO 0
#define EO (Bn*Tn*2)
#define HO (EO + Bn*Tn)
#define CO (HO + Bn*Hn)

__device__ __forceinline__ unsigned short f2bf(float f) {
  union { float f; unsigned u; } v; v.f = f;
  unsigned r = v.u + 0x7FFFu + ((v.u >> 16) & 1u);
  return (unsigned short)(r >> 16);
}
__device__ __forceinline__ float bf2f(unsigned short u) {
  union { unsigned u; float f; } v; v.u = ((unsigned)u) << 16;
  return v.f;
}
__device__ __forceinline__ float sigm(float x) { return 1.f / (1.f + __expf(-x)); }
__device__ __forceinline__ float tanhx(float x) {
  float e = __expf(2.f * x);
  return 1.f - 2.f / (e + 1.f);
}

// L2-point atomics (no sc1 -> executed in the XCD-shared L2, not the LLC).
// Spin must be a real RMW (sc0, returned old): a relaxed atomic load lowers to a plain
// global_load served from stale L1 (round-3 bug).
__device__ __forceinline__ void l2_add_nr(int* p, int v) {
  asm volatile("global_atomic_add %0, %1, off" :: "v"(p), "v"(v) : "memory");
}
__device__ __forceinline__ int l2_add_ret(int* p, int v) {
  int old;
  asm volatile("global_atomic_add %0, %1, %2, off sc0\n\t"
               "s_waitcnt vmcnt(0)"
               : "=v"(old) : "v"(p), "v"(v) : "memory");
  return old;
}
// L1 invalidate that is COMPLETE before returning. buffer_inv is async (counts in vmcnt);
// without the trailing wait, tid0 can enter the final s_barrier with the invalidate still
// in flight, and the other waves' post-barrier loads hit stale L1 (round-4 bug).
__device__ __forceinline__ void l1_inv_sync() {
  asm volatile("buffer_inv\n\ts_waitcnt vmcnt(0)" ::: "memory");
}

// ---------------- weight prep: f32 -> bf16, padded/extended layouts ----------------
__global__ void __launch_bounds__(256) prep_weights(
    const float* __restrict__ Wh, const float* __restrict__ Wi, const float* __restrict__ bbW,
    const float* __restrict__ f1W, const float* __restrict__ f2W,
    const float* __restrict__ taW, const float* __restrict__ tbW, char* __restrict__ ws)
{
  unsigned short* wh = (unsigned short*)(ws + WS_WH);
  unsigned short* bb = (unsigned short*)(ws + WS_BB);
  unsigned short* ff = (unsigned short*)(ws + WS_FF);
  const int n1 = 2048 * KSn, n2 = 128 * KSn, n3 = Hn * BBn;
  const int ntot = n1 + n2 + 4 * n3;
  for (int i = blockIdx.x * blockDim.x + threadIdx.x; i < ntot; i += gridDim.x * blockDim.x) {
    if (i < n1) {
      int c = i / KSn, k = i % KSn;
      float v = (k < 512) ? Wh[c * 512 + k] : ((k < 517) ? Wi[c * 5 + (k - 512)] : 0.f);
      wh[i] = f2bf(v);
    } else if (i < n1 + n2) {
      int j = i - n1; int o = j / KSn, k = j % KSn;
      float v = (k < 512) ? bbW[o * 517 + 5 + k] : ((k < 517) ? bbW[o * 517 + (k - 512)] : 0.f);
      bb[j] = f2bf(v);
    } else {
      int j = i - n1 - n2; int m = j / n3; int r = j % n3;
      const float* src = (m == 0) ? f1W : (m == 1) ? f2W : (m == 2) ? taW : tbW;
      ff[j] = f2bf(src[r]);
    }
  }
}

// ---------------- barriers ----------------
// FAST (probe-validated same-XCD cluster): syncthreads drains stores to the shared L2;
// increment + spin are L2-point RMWs; acquire = completed L1 invalidate (L2 stays warm).
// SLOW (fallback): device-scope threadfence protocol — the round-2 proven path.
__device__ __forceinline__ void cluster_bar(int* ctr, int target, bool fast) {
  __syncthreads();
  if (threadIdx.x == 0) {
    if (fast) {
      l2_add_nr(ctr, 1);
      int tries = 0;
      while (l2_add_ret(ctr, 0) < target) {
        __builtin_amdgcn_s_sleep(1);
        if (++tries >= (1 << 18)) break;   // watchdog: degrade diagnosably, never hang
      }
      l1_inv_sync();
    } else {
      __threadfence();
      atomicAdd(ctr, 1);
      int tries = 0;
      while (__hip_atomic_load(ctr, __ATOMIC_RELAXED, __HIP_MEMORY_SCOPE_AGENT) < target) {
        __builtin_amdgcn_s_sleep(2);
        if (++tries >= (1 << 18)) break;
      }
      __threadfence();
    }
  }
  __syncthreads();
}

// ---------------- main persistent scan kernel ----------------
__global__ void __launch_bounds__(256, 1) ebl_main(
    const float* __restrict__ x,   const float* __restrict__ bi,
    const float* __restrict__ bbb, const float* __restrict__ f1b, const float* __restrict__ f2b,
    const float* __restrict__ tab, const float* __restrict__ tbb,
    const float* __restrict__ predW, const float* __restrict__ predb,
    const float* __restrict__ enW,   const float* __restrict__ enb,
    float* __restrict__ out, char* __restrict__ ws)
{
  extern __shared__ char lds[];
  __shared__ float lbuf[4][16][36];       // [gate/matrix][col][row(padded)] f32
  __shared__ int   pflag;

  unsigned short* hsh = (unsigned short*)(ws + WS_H);
  unsigned short* hls = (unsigned short*)(ws + WS_HL);
  unsigned short* fsh = (unsigned short*)(ws + WS_FEAT);
  const unsigned short* wh  = (const unsigned short*)(ws + WS_WH);
  const unsigned short* bbw = (const unsigned short*)(ws + WS_BB);
  const unsigned short* ffw = (const unsigned short*)(ws + WS_FF);

  const int tid  = threadIdx.x;
  const int lane = tid & 63;
  const int wv   = tid >> 6;              // wave 0..3 = gate / ff-matrix index
  const int cl   = blockIdx.x & 7;        // cluster
  const int wg   = blockIdx.x >> 3;       // 0..31 within cluster
  const int rbase = cl * WPC;             // batch-row base of cluster
  const int jbase = wg * 16;              // hidden-column slice of this WG

  int* cctr = (int*)(ws + WS_BAR) + cl * 32;   // per-cluster main counter
  int* pctr = (int*)(ws + WS_PRB) + cl * 32;   // per-cluster probe counter
  int* dctr = (int*)(ws + WS_DC);              // device startup barrier
  int* xccb = (int*)(ws + WS_XCC);             // per-WG XCC ids
  int* pokb = (int*)(ws + WS_POK);             // per-WG probe verdicts
  int* pdat = (int*)(ws + WS_PDT);             // per-WG probe data slots (stride 16 ints)

  const int l15 = lane & 15;
  const int l4  = lane >> 4;
  const int cc  = tid & 15;               // combine-phase column
  const int rr  = tid >> 4;               // combine-phase row

  // ---- one-time LDS weight residency: Wh slice (64 rows x 544) + ff slice (64 rows x 128) ----
  for (int idx = tid; idx < 64 * 68; idx += 256) {
    int r = idx / 68, ch = idx - r * 68;   // r = g*16 + c
    int g = r >> 4, c = r & 15;
    bf16x8 v = *(const bf16x8*)(wh + (g * 512 + jbase + c) * KSn + ch * 8);
    *(bf16x8*)(lds + LB_WH + r * (KSP * 2) + ch * 16) = v;
  }
  for (int idx = tid; idx < 64 * 16; idx += 256) {
    int r = idx >> 4, ch = idx & 15;       // r = m*16 + c
    int m = r >> 4, c = r & 15;
    bf16x8 v = *(const bf16x8*)(ffw + m * (Hn * BBn) + (jbase + c) * BBn + ch * 8);
    *(bf16x8*)(lds + LB_FF + r * (BBP * 2) + ch * 16) = v;
  }

  // ---- stationary per-thread preloads ----
  float hp0[8], hp1[8], hpe[8];
  if (wv == 0) {
    #pragma unroll
    for (int j = 0; j < 8; ++j) {
      hp0[j] = predW[lane * 8 + j];
      hp1[j] = predW[512 + lane * 8 + j];
      hpe[j] = enW[lane * 8 + j];
    }
  }
  float biC[4];
  #pragma unroll
  for (int g = 0; g < 4; ++g) biC[g] = bi[g * 512 + jbase + cc];
  const float fb1 = f1b[jbase + cc], fb2v = f2b[jbase + cc];
  const float fta = tab[jbase + cc], ftb = tbb[jbase + cc];
  const float bbB = (wg < 8) ? bbb[wg * 16 + l15] : 0.f;

  float cst0 = 0.f, cst1 = 0.f;

  // ---- startup: publish XCC id, x_0; device barrier; XCD-uniformity verdict ----
  int xcc;
  asm volatile("s_getreg_b32 %0, hwreg(HW_REG_XCC_ID)" : "=s"(xcc));
  if (tid == 0) { xccb[blockIdx.x] = xcc; pflag = 1; }
  if (tid < Fn) {
    int b = rbase + wg;
    hsh[b * KSn + 512 + tid] = f2bf(x[(b * Tn + 0) * Fn + tid]);
  }
  cluster_bar(dctr, NWG, false);          // device-scope, full fences

  int refx = xccb[cl];
  int vx   = xccb[cl + 8 * (tid & 31)];
  const bool fast = (__ballot(vx != refx) == 0ull);

  // ---- probe: full DATA propagation through the fast mechanism, twice ----
  // Round 1 tests basic store->bar->remote-read. Round 2 is the real test: round 1's
  // reads pulled the slots into this CU's L1; the rewrite + second bar must be seen
  // through the L1 invalidate (exactly the main loop's reuse pattern). Watchdog trips
  // or stale reads -> pflag=0 -> cluster falls back to the proven slow barrier.
  if (fast) {
    if (tid == 0) pdat[blockIdx.x * 16] = 1000 + blockIdx.x;
    cluster_bar(pctr, WPC, true);
    if (tid < WPC) {
      int g = cl + 8 * tid;
      if (pdat[g * 16] != 1000 + g) pflag = 0;
    }
    __syncthreads();
    if (tid == 0) pdat[blockIdx.x * 16] = 777000 + blockIdx.x * 3;
    cluster_bar(pctr, 2 * WPC, true);
    if (tid < WPC) {
      int g = cl + 8 * tid;
      if (pdat[g * 16] != 777000 + g * 3) pflag = 0;
    }
    __syncthreads();
    if (tid == 0) pokb[blockIdx.x] = pflag;
    __syncthreads();
  }
  cluster_bar(dctr, 2 * NWG, false);      // device-scope: publish pokb

  int pv = pokb[cl + 8 * (tid & 31)];
  const bool fastrun = fast && (__ballot(pv == 0) == 0ull);

  int phase = 0;
  for (int t = 0; t < Tn; ++t) {
    // ---------- fused heads for step t-1 (wave 0; hsh holds h after step t-1) ----------
    if (wv == 0 && t > 0) {
      const int b = rbase + wg;
      const unsigned short* hrow = hsh + b * KSn + lane * 8;
      float s0 = 0.f, s1 = 0.f, se = 0.f;
      #pragma unroll
      for (int j = 0; j < 8; ++j) {
        float hv = bf2f(hrow[j]);
        s0 += hv * hp0[j]; s1 += hv * hp1[j]; se += hv * hpe[j];
      }
      #pragma unroll
      for (int off = 32; off > 0; off >>= 1) {
        s0 += __shfl_down(s0, off);
        s1 += __shfl_down(s1, off);
        se += __shfl_down(se, off);
      }
      if (lane == 0) {
        out[YO + b * (Tn * 2) + (t - 1) * 2 + 0] = s0 + predb[0];
        out[YO + b * (Tn * 2) + (t - 1) * 2 + 1] = s1 + predb[1];
        out[EO + b * Tn + (t - 1)]               = se + enb[0];
      }
    }
    // x_t into hlstm ext cols (consumed by stage B after bar1)
    if (tid < Fn) {
      int b = rbase + wg;
      hls[b * KSn + 512 + tid] = f2bf(x[(b * Tn + t) * Fn + tid]);
    }

    // ---------- stage A: stage h -> LDS; z = [h,x_t] @ Wh^T; gates; h_lstm ----------
    for (int idx = tid; idx < 32 * 68; idx += 256) {
      int r = idx / 68, ch = idx - r * 68;
      bf16x8 v = *(const bf16x8*)(hsh + (rbase + r) * KSn + ch * 8);
      *(bf16x8*)(lds + LB_A + r * (KSP * 2) + ch * 16) = v;
    }
    __syncthreads();
    {
      f32x4 acc0 = {0.f, 0.f, 0.f, 0.f}, acc1 = {0.f, 0.f, 0.f, 0.f};
      const char* a0b = lds + LB_A + l15 * (KSP * 2) + l4 * 16;
      const char* a1b = a0b + 16 * (KSP * 2);
      const char* wb  = lds + LB_WH + (wv * 16 + l15) * (KSP * 2) + l4 * 16;
      #pragma unroll
      for (int ks = 0; ks < 17; ++ks) {
        bf16x8 a0 = *(const bf16x8*)(a0b + ks * 64);
        bf16x8 a1 = *(const bf16x8*)(a1b + ks * 64);
        bf16x8 b8 = *(const bf16x8*)(wb + ks * 64);
        acc0 = __builtin_amdgcn_mfma_f32_16x16x32_bf16(a0, b8, acc0, 0, 0, 0);
        acc1 = __builtin_amdgcn_mfma_f32_16x16x32_bf16(a1, b8, acc1, 0, 0, 0);
      }
      *(f32x4*)(&lbuf[wv][l15][l4 * 4])      = acc0;
      *(f32x4*)(&lbuf[wv][l15][16 + l4 * 4]) = acc1;
    }
    __syncthreads();
    {
      float zi0 = lbuf[0][cc][rr]      + biC[0];
      float zg0 = lbuf[1][cc][rr]      + biC[1];
      float zf0 = lbuf[2][cc][rr]      + biC[2];
      float zo0 = lbuf[3][cc][rr]      + biC[3];
      float zi1 = lbuf[0][cc][rr + 16] + biC[0];
      float zg1 = lbuf[1][cc][rr + 16] + biC[1];
      float zf1 = lbuf[2][cc][rr + 16] + biC[2];
      float zo1 = lbuf[3][cc][rr + 16] + biC[3];
      float cn0 = cst0 * sigm(zf0 + 1.f) + tanhx(zi0) * sigm(zg0);
      float cn1 = cst1 * sigm(zf1 + 1.f) + tanhx(zi1) * sigm(zg1);
      float hl0 = tanhx(cn0) * sigm(zo0);
      float hl1 = tanhx(cn1) * sigm(zo1);
      cst0 = cn0; cst1 = cn1;
      const int b0 = rbase + rr, b1 = rbase + rr + 16;
      hls[b0 * KSn + jbase + cc] = f2bf(hl0);
      hls[b1 * KSn + jbase + cc] = f2bf(hl1);
      if (t == Tn - 1) {
        out[CO + b0 * Hn + jbase + cc] = cn0;
        out[CO + b1 * Hn + jbase + cc] = cn1;
      }
    }
    ++phase; cluster_bar(cctr, phase * WPC, fastrun);

    // ---------- stage B: feat = lecun_tanh([h_lstm,x_t] @ bb^T) (WGs 0..7) ----------
    if (wg < 8) {
      for (int idx = tid; idx < 32 * 68; idx += 256) {
        int r = idx / 68, ch = idx - r * 68;
        bf16x8 v = *(const bf16x8*)(hls + (rbase + r) * KSn + ch * 8);
        *(bf16x8*)(lds + LB_A + r * (KSP * 2) + ch * 16) = v;
      }
      __syncthreads();
      if (wv < 2) {
        f32x4 accB = {0.f, 0.f, 0.f, 0.f};
        const char* ab = lds + LB_A + (wv * 16 + l15) * (KSP * 2) + l4 * 16;
        const unsigned short* brow = bbw + (wg * 16 + l15) * KSn + l4 * 8;
        #pragma unroll
        for (int ks = 0; ks < 17; ++ks) {
          bf16x8 a  = *(const bf16x8*)(ab + ks * 64);
          bf16x8 b8 = *(const bf16x8*)(brow + ks * 32);
          accB = __builtin_amdgcn_mfma_f32_16x16x32_bf16(a, b8, accB, 0, 0, 0);
        }
        #pragma unroll
        for (int j = 0; j < 4; ++j) {
          float v = accB[j] + bbB;
          v = 1.7159f * tanhx(0.666f * v);
          int b = rbase + wv * 16 + l4 * 4 + j;
          fsh[b * BBn + wg * 16 + l15] = f2bf(v);
        }
      }
    }
    ++phase; cluster_bar(cctr, phase * WPC, fastrun);

    // ---------- stage C: stage feat -> LDS; ff1/ff2/ta/tb; h_new ----------
    for (int idx = tid; idx < 32 * 16; idx += 256) {
      int r = idx >> 4, ch = idx & 15;
      bf16x8 v = *(const bf16x8*)(fsh + (rbase + r) * BBn + ch * 8);
      *(bf16x8*)(lds + LB_A + r * (BBP * 2) + ch * 16) = v;
    }
    __syncthreads();
    {
      f32x4 ac0 = {0.f, 0.f, 0.f, 0.f}, ac1 = {0.f, 0.f, 0.f, 0.f};
      const char* a0b = lds + LB_A + l15 * (BBP * 2) + l4 * 16;
      const char* a1b = a0b + 16 * (BBP * 2);
      const char* wb  = lds + LB_FF + (wv * 16 + l15) * (BBP * 2) + l4 * 16;
      #pragma unroll
      for (int ks = 0; ks < 4; ++ks) {
        bf16x8 a0 = *(const bf16x8*)(a0b + ks * 64);
        bf16x8 a1 = *(const bf16x8*)(a1b + ks * 64);
        bf16x8 b8 = *(const bf16x8*)(wb + ks * 64);
        ac0 = __builtin_amdgcn_mfma_f32_16x16x32_bf16(a0, b8, ac0, 0, 0, 0);
        ac1 = __builtin_amdgcn_mfma_f32_16x16x32_bf16(a1, b8, ac1, 0, 0, 0);
      }
      *(f32x4*)(&lbuf[wv][l15][l4 * 4])      = ac0;
      *(f32x4*)(&lbuf[wv][l15][16 + l4 * 4]) = ac1;
    }
    __syncthreads();
    {
      float p10 = lbuf[0][cc][rr] + fb1,      p20 = lbuf[1][cc][rr] + fb2v;
      float pa0 = lbuf[2][cc][rr] + fta,      pb0 = lbuf[3][cc][rr] + ftb;
      float p11 = lbuf[0][cc][rr + 16] + fb1, p21 = lbuf[1][cc][rr + 16] + fb2v;
      float pa1 = lbuf[2][cc][rr + 16] + fta, pb1 = lbuf[3][cc][rr + 16] + ftb;
      float f10 = tanhx(p10), f20 = tanhx(p20), ti0 = sigm(pa0 + pb0);
      float f11 = tanhx(p11), f21 = tanhx(p21), ti1 = sigm(pa1 + pb1);
      float hn0 = f10 + ti0 * (f20 - f10);
      float hn1 = f11 + ti1 * (f21 - f11);
      const int b0 = rbase + rr, b1 = rbase + rr + 16;
      hsh[b0 * KSn + jbase + cc] = f2bf(hn0);
      hsh[b1 * KSn + jbase + cc] = f2bf(hn1);
      if (t == Tn - 1) {
        out[HO + b0 * Hn + jbase + cc] = hn0;
        out[HO + b1 * Hn + jbase + cc] = hn1;
      }
    }
    if (t + 1 < Tn && tid < Fn) {
      int b = rbase + wg;
      hsh[b * KSn + 512 + tid] = f2bf(x[(b * Tn + t + 1) * Fn + tid]);
    }
    ++phase; cluster_bar(cctr, phase * WPC, fastrun);
  }

  // ---------- epilogue heads for t = Tn-1 ----------
  if (wv == 0) {
    const int b = rbase + wg;
    const unsigned short* hrow = hsh + b * KSn + lane * 8;
    float s0 = 0.f, s1 = 0.f, se = 0.f;
    #pragma unroll
    for (int j = 0; j < 8; ++j) {
      float hv = bf2f(hrow[j]);
      s0 += hv * hp0[j]; s1 += hv * hp1[j]; se += hv * hpe[j];
    }
    #pragma unroll
    for (int off = 32; off > 0; off >>= 1) {
      s0 += __shfl_down(s0, off);
      s1 += __shfl_down(s1, off);
      se += __shfl_down(se, off);
    }
    if (lane == 0) {
      out[YO + b * (Tn * 2) + (Tn - 1) * 2 + 0] = s0 + predb[0];
      out[YO + b * (Tn * 2) + (Tn - 1) * 2 + 1] = s1 + predb[1];
      out[EO + b * Tn + (Tn - 1)]               = se + enb[0];
    }
  }
}

extern "C" void kernel_launch(void* const* d_in, const int* in_sizes, int n_in,
                              void* d_out, int out_size, void* d_ws, size_t ws_size,
                              hipStream_t stream) {
  const float* x   = (const float*)d_in[0];
  const float* Wi  = (const float*)d_in[1];
  const float* bi  = (const float*)d_in[2];
  const float* Wh  = (const float*)d_in[3];
  const float* bbW = (const float*)d_in[4];
  const float* bbb = (const float*)d_in[5];
  const float* f1W = (const float*)d_in[6];
  const float* f1b = (const float*)d_in[7];
  const float* f2W = (const float*)d_in[8];
  const float* f2b = (const float*)d_in[9];
  const float* taW = (const float*)d_in[10];
  const float* tab = (const float*)d_in[11];
  const float* tbW = (const float*)d_in[12];
  const float* tbb = (const float*)d_in[13];
  const float* pW  = (const float*)d_in[14];
  const float* pb  = (const float*)d_in[15];
  const float* eW  = (const float*)d_in[16];
  const float* eb  = (const float*)d_in[17];
  float* out = (float*)d_out;
  char* ws = (char*)d_ws;

  static_assert(DYN_LDS == 123392, "LDS layout");
  (void)hipFuncSetAttribute((const void*)ebl_main,
                            hipFuncAttributeMaxDynamicSharedMemorySize, DYN_LDS);

  // zero barriers + verdict/probe tables + activation buffers (replayed every launch)
  hipMemsetAsync(ws, 0, WS_WH, stream);
  prep_weights<<<2048, 256, 0, stream>>>(Wh, Wi, bbW, f1W, f2W, taW, tbW, ws);

  void* args[] = { (void*)&x, (void*)&bi, (void*)&bbb, (void*)&f1b, (void*)&f2b,
                   (void*)&tab, (void*)&tbb, (void*)&pW, (void*)&pb, (void*)&eW,
                   (void*)&eb, (void*)&out, (void*)&ws };
  hipLaunchCooperativeKernel((const void*)ebl_main, dim3(NWG), dim3(256), args,
                             DYN_LDS, stream);
}

// Round 6
// 22808.929 us; speedup vs baseline: 1.0008x; 1.0008x over previous
//
#include <hip/hip_runtime.h>

// ---- problem dims ----
#define Bn   256
#define Tn   512
#define Fn   5
#define Hn   512
#define BBn  128
#define KSn  544          // 512 (H) + 5 (x) + pad to 17*32
#define KSP  552          // LDS row stride (shorts) for 544-col tiles: +8 -> 2-way banks only
#define BBP  136          // LDS row stride (shorts) for 128-col tiles
#define NC   8            // clusters (XCD round-robin by blockIdx%8 — verified at runtime, not assumed)
#define WPC  32           // workgroups per cluster
#define NWG  (NC*WPC)

typedef __attribute__((ext_vector_type(8))) short bf16x8;
typedef __attribute__((ext_vector_type(4))) float f32x4;

// ---- d_ws layout (bytes) ----
#define WS_BAR   0                        // per-cluster main counters, 128B apart (8 x 128B)
#define WS_PRB   1024                     // per-cluster probe counters, 128B apart
#define WS_DC    2048                     // device-wide startup barrier counter
#define WS_XCC   4096                     // per-WG XCC id table (256 ints)
#define WS_POK   5120                     // per-WG probe-ok table (256 ints)
#define WS_PDT   6144                     // per-WG probe data slots (256 x 64B)
#define WS_H     24576                    // h_shared [Bn][KSn] bf16 (cols 512..516 = x_t, rest 0)
#define WS_HL    (WS_H   + Bn*KSn*2)      // hlstm    [Bn][KSn] bf16
#define WS_FEAT  (WS_HL  + Bn*KSn*2)      // feat     [Bn][BBn] bf16
#define WS_WH    (WS_FEAT + Bn*BBn*2)     // Wh_ext   [2048][KSn] bf16 (k>=512 -> Wi, pad 0)
#define WS_BB    (WS_WH  + 2048*KSn*2)    // bb_ext   [128][KSn] bf16
#define WS_FF    (WS_BB  + 128*KSn*2)     // ff       [4][Hn][BBn] bf16

// ---- dynamic LDS layout (bytes) ----
#define LB_A     0                        // activation stage: 32*KSP*2 = 35328 (reused: h / hlstm / feat)
#define LB_WH    (LB_A + 32*KSP*2)        // Wh slice: [4 gates][16 cols][KSP] = 70656
#define LB_FF    (LB_WH + 64*KSP*2)       // ff slice: [4 mats][16 cols][BBP] = 17408
#define DYN_LDS  (LB_FF + 64*BBP*2)       // = 123392 B (+9216 static lbuf = 132608 <= 160K)

// ---- d_out layout (floats) ----
#define YO 0
#define EO (Bn*Tn*2)
#define HO (EO + Bn*Tn)
#define CO (HO + Bn*Hn)

__device__ __forceinline__ unsigned short f2bf(float f) {
  union { float f; unsigned u; } v; v.f = f;
  unsigned r = v.u + 0x7FFFu + ((v.u >> 16) & 1u);
  return (unsigned short)(r >> 16);
}
__device__ __forceinline__ float bf2f(unsigned short u) {
  union { unsigned u; float f; } v; v.u = ((unsigned)u) << 16;
  return v.f;
}
__device__ __forceinline__ float sigm(float x) { return 1.f / (1.f + __expf(-x)); }
__device__ __forceinline__ float tanhx(float x) {
  float e = __expf(2.f * x);
  return 1.f - 2.f / (e + 1.f);
}

// L2-point atomics (no sc1 -> executed in the XCD-shared L2, not the LLC).
// Spin must be a real RMW (sc0, returned old): a relaxed atomic load lowers to a plain
// global_load served from stale L1 (round-3 bug).
__device__ __forceinline__ void l2_add_nr(int* p, int v) {
  asm volatile("global_atomic_add %0, %1, off" :: "v"(p), "v"(v) : "memory");
}
__device__ __forceinline__ int l2_add_ret(int* p, int v) {
  int old;
  asm volatile("global_atomic_add %0, %1, %2, off sc0\n\t"
               "s_waitcnt vmcnt(0)"
               : "=v"(old) : "v"(p), "v"(v) : "memory");
  return old;
}
// Per-wave L1 invalidate. Round-5 lesson: a single wave's buffer_inv does NOT reliably
// invalidate L1 before OTHER waves' post-barrier loads (cross-wave race; inv completion
// not observable from another wave). Same-wave VMEM streams are issued in order, so each
// wave invalidating immediately before its own loads is the one ordering the HW (and
// LLVM's own acquire lowering) guarantees. vmcnt(0) is a no-op if inv doesn't count.
__device__ __forceinline__ void l1_inv_wave() {
  asm volatile("buffer_inv\n\ts_waitcnt vmcnt(0)" ::: "memory");
}

// ---------------- weight prep: f32 -> bf16, padded/extended layouts ----------------
__global__ void __launch_bounds__(256) prep_weights(
    const float* __restrict__ Wh, const float* __restrict__ Wi, const float* __restrict__ bbW,
    const float* __restrict__ f1W, const float* __restrict__ f2W,
    const float* __restrict__ taW, const float* __restrict__ tbW, char* __restrict__ ws)
{
  unsigned short* wh = (unsigned short*)(ws + WS_WH);
  unsigned short* bb = (unsigned short*)(ws + WS_BB);
  unsigned short* ff = (unsigned short*)(ws + WS_FF);
  const int n1 = 2048 * KSn, n2 = 128 * KSn, n3 = Hn * BBn;
  const int ntot = n1 + n2 + 4 * n3;
  for (int i = blockIdx.x * blockDim.x + threadIdx.x; i < ntot; i += gridDim.x * blockDim.x) {
    if (i < n1) {
      int c = i / KSn, k = i % KSn;
      float v = (k < 512) ? Wh[c * 512 + k] : ((k < 517) ? Wi[c * 5 + (k - 512)] : 0.f);
      wh[i] = f2bf(v);
    } else if (i < n1 + n2) {
      int j = i - n1; int o = j / KSn, k = j % KSn;
      float v = (k < 512) ? bbW[o * 517 + 5 + k] : ((k < 517) ? bbW[o * 517 + (k - 512)] : 0.f);
      bb[j] = f2bf(v);
    } else {
      int j = i - n1 - n2; int m = j / n3; int r = j % n3;
      const float* src = (m == 0) ? f1W : (m == 1) ? f2W : (m == 2) ? taW : tbW;
      ff[j] = f2bf(src[r]);
    }
  }
}

// ---------------- barriers ----------------
// FAST (probe-validated same-XCD cluster): syncthreads drains stores to the shared L2;
// tid0 does L2-point RMW inc + spin; releasing syncthreads; then EVERY WAVE invalidates
// its L1 before its own subsequent loads (same-wave ordering). L2 stays warm.
// SLOW (fallback): device-scope threadfence protocol — the round-2 proven path.
__device__ __forceinline__ void cluster_bar(int* ctr, int target, bool fast) {
  __syncthreads();
  if (fast) {
    if (threadIdx.x == 0) {
      l2_add_nr(ctr, 1);
      int tries = 0;
      while (l2_add_ret(ctr, 0) < target) {
        __builtin_amdgcn_s_sleep(1);
        if (++tries >= (1 << 18)) break;   // watchdog: degrade diagnosably, never hang
      }
    }
    __syncthreads();
    l1_inv_wave();                         // per-wave acquire
  } else {
    if (threadIdx.x == 0) {
      __threadfence();
      atomicAdd(ctr, 1);
      int tries = 0;
      while (__hip_atomic_load(ctr, __ATOMIC_RELAXED, __HIP_MEMORY_SCOPE_AGENT) < target) {
        __builtin_amdgcn_s_sleep(2);
        if (++tries >= (1 << 18)) break;
      }
      __threadfence();
    }
    __syncthreads();
  }
}

// ---------------- main persistent scan kernel ----------------
__global__ void __launch_bounds__(256, 1) ebl_main(
    const float* __restrict__ x,   const float* __restrict__ bi,
    const float* __restrict__ bbb, const float* __restrict__ f1b, const float* __restrict__ f2b,
    const float* __restrict__ tab, const float* __restrict__ tbb,
    const float* __restrict__ predW, const float* __restrict__ predb,
    const float* __restrict__ enW,   const float* __restrict__ enb,
    float* __restrict__ out, char* __restrict__ ws)
{
  extern __shared__ char lds[];
  __shared__ float lbuf[4][16][36];       // [gate/matrix][col][row(padded)] f32
  __shared__ int   pflag;

  unsigned short* hsh = (unsigned short*)(ws + WS_H);
  unsigned short* hls = (unsigned short*)(ws + WS_HL);
  unsigned short* fsh = (unsigned short*)(ws + WS_FEAT);
  const unsigned short* wh  = (const unsigned short*)(ws + WS_WH);
  const unsigned short* bbw = (const unsigned short*)(ws + WS_BB);
  const unsigned short* ffw = (const unsigned short*)(ws + WS_FF);

  const int tid  = threadIdx.x;
  const int lane = tid & 63;
  const int wv   = tid >> 6;              // wave 0..3 = gate / ff-matrix index
  const int cl   = blockIdx.x & 7;        // cluster
  const int wg   = blockIdx.x >> 3;       // 0..31 within cluster
  const int rbase = cl * WPC;             // batch-row base of cluster
  const int jbase = wg * 16;              // hidden-column slice of this WG

  int* cctr = (int*)(ws + WS_BAR) + cl * 32;   // per-cluster main counter
  int* pctr = (int*)(ws + WS_PRB) + cl * 32;   // per-cluster probe counter
  int* dctr = (int*)(ws + WS_DC);              // device startup barrier
  int* xccb = (int*)(ws + WS_XCC);             // per-WG XCC ids
  int* pokb = (int*)(ws + WS_POK);             // per-WG probe verdicts
  int* pdat = (int*)(ws + WS_PDT);             // per-WG probe data slots (stride 16 ints)

  const int l15 = lane & 15;
  const int l4  = lane >> 4;
  const int cc  = tid & 15;               // combine-phase column
  const int rr  = tid >> 4;               // combine-phase row

  // ---- one-time LDS weight residency: Wh slice (64 rows x 544) + ff slice (64 rows x 128) ----
  for (int idx = tid; idx < 64 * 68; idx += 256) {
    int r = idx / 68, ch = idx - r * 68;   // r = g*16 + c
    int g = r >> 4, c = r & 15;
    bf16x8 v = *(const bf16x8*)(wh + (g * 512 + jbase + c) * KSn + ch * 8);
    *(bf16x8*)(lds + LB_WH + r * (KSP * 2) + ch * 16) = v;
  }
  for (int idx = tid; idx < 64 * 16; idx += 256) {
    int r = idx >> 4, ch = idx & 15;       // r = m*16 + c
    int m = r >> 4, c = r & 15;
    bf16x8 v = *(const bf16x8*)(ffw + m * (Hn * BBn) + (jbase + c) * BBn + ch * 8);
    *(bf16x8*)(lds + LB_FF + r * (BBP * 2) + ch * 16) = v;
  }

  // ---- stationary per-thread preloads ----
  float hp0[8], hp1[8], hpe[8];
  if (wv == 0) {
    #pragma unroll
    for (int j = 0; j < 8; ++j) {
      hp0[j] = predW[lane * 8 + j];
      hp1[j] = predW[512 + lane * 8 + j];
      hpe[j] = enW[lane * 8 + j];
    }
  }
  float biC[4];
  #pragma unroll
  for (int g = 0; g < 4; ++g) biC[g] = bi[g * 512 + jbase + cc];
  const float fb1 = f1b[jbase + cc], fb2v = f2b[jbase + cc];
  const float fta = tab[jbase + cc], ftb = tbb[jbase + cc];
  const float bbB = (wg < 8) ? bbb[wg * 16 + l15] : 0.f;

  float cst0 = 0.f, cst1 = 0.f;

  // ---- startup: publish XCC id, x_0; device barrier; XCD-uniformity verdict ----
  int xcc;
  asm volatile("s_getreg_b32 %0, hwreg(HW_REG_XCC_ID)" : "=s"(xcc));
  if (tid == 0) { xccb[blockIdx.x] = xcc; pflag = 1; }
  if (tid < Fn) {
    int b = rbase + wg;
    hsh[b * KSn + 512 + tid] = f2bf(x[(b * Tn + 0) * Fn + tid]);
  }
  cluster_bar(dctr, NWG, false);          // device-scope, full fences

  int refx = xccb[cl];
  int vx   = xccb[cl + 8 * (tid & 31)];
  const bool fast = (__ballot(vx != refx) == 0ull);

  // ---- probe: full DATA propagation through the fast mechanism, twice, ALL waves ----
  // Round 1: store -> fast-bar -> remote read (cold L1). Round 2 is the real test:
  // round-1 reads pulled the slots into this CU's L1; the rewrite + second fast-bar must
  // be seen through each wave's own L1 invalidate — exactly the main loop's reuse
  // pattern, checked by every wave. Any failure -> slow fallback (round-2 proven).
  if (fast) {
    if (tid == 0) pdat[blockIdx.x * 16] = 1000 + blockIdx.x;
    cluster_bar(pctr, WPC, true);
    {
      int g = cl + 8 * (tid & 31);
      if (pdat[g * 16] != 1000 + g) pflag = 0;
    }
    __syncthreads();
    if (tid == 0) pdat[blockIdx.x * 16] = 777000 + blockIdx.x * 3;
    cluster_bar(pctr, 2 * WPC, true);
    {
      int g = cl + 8 * (tid & 31);
      if (pdat[g * 16] != 777000 + g * 3) pflag = 0;
    }
    __syncthreads();
    if (tid == 0) pokb[blockIdx.x] = pflag;
    __syncthreads();
  }
  cluster_bar(dctr, 2 * NWG, false);      // device-scope: publish pokb

  int pv = pokb[cl + 8 * (tid & 31)];
  const bool fastrun = fast && (__ballot(pv == 0) == 0ull);

  int phase = 0;
  for (int t = 0; t < Tn; ++t) {
    // ---------- fused heads for step t-1 (wave 0; hsh holds h after step t-1) ----------
    if (wv == 0 && t > 0) {
      const int b = rbase + wg;
      const unsigned short* hrow = hsh + b * KSn + lane * 8;
      float s0 = 0.f, s1 = 0.f, se = 0.f;
      #pragma unroll
      for (int j = 0; j < 8; ++j) {
        float hv = bf2f(hrow[j]);
        s0 += hv * hp0[j]; s1 += hv * hp1[j]; se += hv * hpe[j];
      }
      #pragma unroll
      for (int off = 32; off > 0; off >>= 1) {
        s0 += __shfl_down(s0, off);
        s1 += __shfl_down(s1, off);
        se += __shfl_down(se, off);
      }
      if (lane == 0) {
        out[YO + b * (Tn * 2) + (t - 1) * 2 + 0] = s0 + predb[0];
        out[YO + b * (Tn * 2) + (t - 1) * 2 + 1] = s1 + predb[1];
        out[EO + b * Tn + (t - 1)]               = se + enb[0];
      }
    }
    // x_t into hlstm ext cols (consumed by stage B after bar1)
    if (tid < Fn) {
      int b = rbase + wg;
      hls[b * KSn + 512 + tid] = f2bf(x[(b * Tn + t) * Fn + tid]);
    }

    // ---------- stage A: stage h -> LDS; z = [h,x_t] @ Wh^T; gates; h_lstm ----------
    for (int idx = tid; idx < 32 * 68; idx += 256) {
      int r = idx / 68, ch = idx - r * 68;
      bf16x8 v = *(const bf16x8*)(hsh + (rbase + r) * KSn + ch * 8);
      *(bf16x8*)(lds + LB_A + r * (KSP * 2) + ch * 16) = v;
    }
    __syncthreads();
    {
      f32x4 acc0 = {0.f, 0.f, 0.f, 0.f}, acc1 = {0.f, 0.f, 0.f, 0.f};
      const char* a0b = lds + LB_A + l15 * (KSP * 2) + l4 * 16;
      const char* a1b = a0b + 16 * (KSP * 2);
      const char* wb  = lds + LB_WH + (wv * 16 + l15) * (KSP * 2) + l4 * 16;
      #pragma unroll
      for (int ks = 0; ks < 17; ++ks) {
        bf16x8 a0 = *(const bf16x8*)(a0b + ks * 64);
        bf16x8 a1 = *(const bf16x8*)(a1b + ks * 64);
        bf16x8 b8 = *(const bf16x8*)(wb + ks * 64);
        acc0 = __builtin_amdgcn_mfma_f32_16x16x32_bf16(a0, b8, acc0, 0, 0, 0);
        acc1 = __builtin_amdgcn_mfma_f32_16x16x32_bf16(a1, b8, acc1, 0, 0, 0);
      }
      *(f32x4*)(&lbuf[wv][l15][l4 * 4])      = acc0;
      *(f32x4*)(&lbuf[wv][l15][16 + l4 * 4]) = acc1;
    }
    __syncthreads();
    {
      float zi0 = lbuf[0][cc][rr]      + biC[0];
      float zg0 = lbuf[1][cc][rr]      + biC[1];
      float zf0 = lbuf[2][cc][rr]      + biC[2];
      float zo0 = lbuf[3][cc][rr]      + biC[3];
      float zi1 = lbuf[0][cc][rr + 16] + biC[0];
      float zg1 = lbuf[1][cc][rr + 16] + biC[1];
      float zf1 = lbuf[2][cc][rr + 16] + biC[2];
      float zo1 = lbuf[3][cc][rr + 16] + biC[3];
      float cn0 = cst0 * sigm(zf0 + 1.f) + tanhx(zi0) * sigm(zg0);
      float cn1 = cst1 * sigm(zf1 + 1.f) + tanhx(zi1) * sigm(zg1);
      float hl0 = tanhx(cn0) * sigm(zo0);
      float hl1 = tanhx(cn1) * sigm(zo1);
      cst0 = cn0; cst1 = cn1;
      const int b0 = rbase + rr, b1 = rbase + rr + 16;
      hls[b0 * KSn + jbase + cc] = f2bf(hl0);
      hls[b1 * KSn + jbase + cc] = f2bf(hl1);
      if (t == Tn - 1) {
        out[CO + b0 * Hn + jbase + cc] = cn0;
        out[CO + b1 * Hn + jbase + cc] = cn1;
      }
    }
    ++phase; cluster_bar(cctr, phase * WPC, fastrun);

    // ---------- stage B: feat = lecun_tanh([h_lstm,x_t] @ bb^T) (WGs 0..7) ----------
    if (wg < 8) {
      for (int idx = tid; idx < 32 * 68; idx += 256) {
        int r = idx / 68, ch = idx - r * 68;
        bf16x8 v = *(const bf16x8*)(hls + (rbase + r) * KSn + ch * 8);
        *(bf16x8*)(lds + LB_A + r * (KSP * 2) + ch * 16) = v;
      }
      __syncthreads();
      if (wv < 2) {
        f32x4 accB = {0.f, 0.f, 0.f, 0.f};
        const char* ab = lds + LB_A + (wv * 16 + l15) * (KSP * 2) + l4 * 16;
        const unsigned short* brow = bbw + (wg * 16 + l15) * KSn + l4 * 8;
        #pragma unroll
        for (int ks = 0; ks < 17; ++ks) {
          bf16x8 a  = *(const bf16x8*)(ab + ks * 64);
          bf16x8 b8 = *(const bf16x8*)(brow + ks * 32);
          accB = __builtin_amdgcn_mfma_f32_16x16x32_bf16(a, b8, accB, 0, 0, 0);
        }
        #pragma unroll
        for (int j = 0; j < 4; ++j) {
          float v = accB[j] + bbB;
          v = 1.7159f * tanhx(0.666f * v);
          int b = rbase + wv * 16 + l4 * 4 + j;
          fsh[b * BBn + wg * 16 + l15] = f2bf(v);
        }
      }
    }
    ++phase; cluster_bar(cctr, phase * WPC, fastrun);

    // ---------- stage C: stage feat -> LDS; ff1/ff2/ta/tb; h_new ----------
    for (int idx = tid; idx < 32 * 16; idx += 256) {
      int r = idx >> 4, ch = idx & 15;
      bf16x8 v = *(const bf16x8*)(fsh + (rbase + r) * BBn + ch * 8);
      *(bf16x8*)(lds + LB_A + r * (BBP * 2) + ch * 16) = v;
    }
    __syncthreads();
    {
      f32x4 ac0 = {0.f, 0.f, 0.f, 0.f}, ac1 = {0.f, 0.f, 0.f, 0.f};
      const char* a0b = lds + LB_A + l15 * (BBP * 2) + l4 * 16;
      const char* a1b = a0b + 16 * (BBP * 2);
      const char* wb  = lds + LB_FF + (wv * 16 + l15) * (BBP * 2) + l4 * 16;
      #pragma unroll
      for (int ks = 0; ks < 4; ++ks) {
        bf16x8 a0 = *(const bf16x8*)(a0b + ks * 64);
        bf16x8 a1 = *(const bf16x8*)(a1b + ks * 64);
        bf16x8 b8 = *(const bf16x8*)(wb + ks * 64);
        ac0 = __builtin_amdgcn_mfma_f32_16x16x32_bf16(a0, b8, ac0, 0, 0, 0);
        ac1 = __builtin_amdgcn_mfma_f32_16x16x32_bf16(a1, b8, ac1, 0, 0, 0);
      }
      *(f32x4*)(&lbuf[wv][l15][l4 * 4])      = ac0;
      *(f32x4*)(&lbuf[wv][l15][16 + l4 * 4]) = ac1;
    }
    __syncthreads();
    {
      float p10 = lbuf[0][cc][rr] + fb1,      p20 = lbuf[1][cc][rr] + fb2v;
      float pa0 = lbuf[2][cc][rr] + fta,      pb0 = lbuf[3][cc][rr] + ftb;
      float p11 = lbuf[0][cc][rr + 16] + fb1, p21 = lbuf[1][cc][rr + 16] + fb2v;
      float pa1 = lbuf[2][cc][rr + 16] + fta, pb1 = lbuf[3][cc][rr + 16] + ftb;
      float f10 = tanhx(p10), f20 = tanhx(p20), ti0 = sigm(pa0 + pb0);
      float f11 = tanhx(p11), f21 = tanhx(p21), ti1 = sigm(pa1 + pb1);
      float hn0 = f10 + ti0 * (f20 - f10);
      float hn1 = f11 + ti1 * (f21 - f11);
      const int b0 = rbase + rr, b1 = rbase + rr + 16;
      hsh[b0 * KSn + jbase + cc] = f2bf(hn0);
      hsh[b1 * KSn + jbase + cc] = f2bf(hn1);
      if (t == Tn - 1) {
        out[HO + b0 * Hn + jbase + cc] = hn0;
        out[HO + b1 * Hn + jbase + cc] = hn1;
      }
    }
    if (t + 1 < Tn && tid < Fn) {
      int b = rbase + wg;
      hsh[b * KSn + 512 + tid] = f2bf(x[(b * Tn + t + 1) * Fn + tid]);
    }
    ++phase; cluster_bar(cctr, phase * WPC, fastrun);
  }

  // ---------- epilogue heads for t = Tn-1 ----------
  if (wv == 0) {
    const int b = rbase + wg;
    const unsigned short* hrow = hsh + b * KSn + lane * 8;
    float s0 = 0.f, s1 = 0.f, se = 0.f;
    #pragma unroll
    for (int j = 0; j < 8; ++j) {
      float hv = bf2f(hrow[j]);
      s0 += hv * hp0[j]; s1 += hv * hp1[j]; se += hv * hpe[j];
    }
    #pragma unroll
    for (int off = 32; off > 0; off >>= 1) {
      s0 += __shfl_down(s0, off);
      s1 += __shfl_down(s1, off);
      se += __shfl_down(se, off);
    }
    if (lane == 0) {
      out[YO + b * (Tn * 2) + (Tn - 1) * 2 + 0] = s0 + predb[0];
      out[YO + b * (Tn * 2) + (Tn - 1) * 2 + 1] = s1 + predb[1];
      out[EO + b * Tn + (Tn - 1)]               = se + enb[0];
    }
  }
}

extern "C" void kernel_launch(void* const* d_in, const int* in_sizes, int n_in,
                              void* d_out, int out_size, void* d_ws, size_t ws_size,
                              hipStream_t stream) {
  const float* x   = (const float*)d_in[0];
  const float* Wi  = (const float*)d_in[1];
  const float* bi  = (const float*)d_in[2];
  const float* Wh  = (const float*)d_in[3];
  const float* bbW = (const float*)d_in[4];
  const float* bbb = (const float*)d_in[5];
  const float* f1W = (const float*)d_in[6];
  const float* f1b = (const float*)d_in[7];
  const float* f2W = (const float*)d_in[8];
  const float* f2b = (const float*)d_in[9];
  const float* taW = (const float*)d_in[10];
  const float* tab = (const float*)d_in[11];
  const float* tbW = (const float*)d_in[12];
  const float* tbb = (const float*)d_in[13];
  const float* pW  = (const float*)d_in[14];
  const float* pb  = (const float*)d_in[15];
  const float* eW  = (const float*)d_in[16];
  const float* eb  = (const float*)d_in[17];
  float* out = (float*)d_out;
  char* ws = (char*)d_ws;

  static_assert(DYN_LDS == 123392, "LDS layout");
  (void)hipFuncSetAttribute((const void*)ebl_main,
                            hipFuncAttributeMaxDynamicSharedMemorySize, DYN_LDS);

  // zero barriers + verdict/probe tables + activation buffers (replayed every launch)
  hipMemsetAsync(ws, 0, WS_WH, stream);
  prep_weights<<<2048, 256, 0, stream>>>(Wh, Wi, bbW, f1W, f2W, taW, tbW, ws);

  void* args[] = { (void*)&x, (void*)&bi, (void*)&bbb, (void*)&f1b, (void*)&f2b,
                   (void*)&tab, (void*)&tbb, (void*)&pW, (void*)&pb, (void*)&eW,
                   (void*)&eb, (void*)&out, (void*)&ws };
  hipLaunchCooperativeKernel((const void*)ebl_main, dim3(NWG), dim3(256), args,
                             DYN_LDS, stream);
}

// Round 7
// 9244.695 us; speedup vs baseline: 2.4693x; 2.4672x over previous
//
#include <hip/hip_runtime.h>

// ---- problem dims ----
#define Bn   256
#define Tn   512
#define Fn   5
#define Hn   512
#define BBn  128
#define KSn  544          // 512 (H) + 5 (x) + pad to 17*32
#define KSP  552          // LDS row stride (shorts) for 544-col tiles: +8 -> 2-way banks only
#define BBP  136          // LDS row stride (shorts) for 128-col tiles
#define NC   8            // clusters (XCD round-robin by blockIdx%8 — verified at runtime, not assumed)
#define WPC  32           // workgroups per cluster
#define NWG  (NC*WPC)

typedef __attribute__((ext_vector_type(8))) short bf16x8;
typedef __attribute__((ext_vector_type(4))) float f32x4;
typedef unsigned long long u64;

// ---- d_ws layout (bytes) ----
#define WS_BAR   0                        // per-cluster main counters, 128B apart (8 x 128B)
#define WS_PRB   1024                     // per-cluster probe counters, 128B apart
#define WS_DC    2048                     // device-wide startup barrier counter
#define WS_XCC   4096                     // per-WG XCC id table (256 ints)
#define WS_POK   5120                     // per-WG probe-ok table (256 ints)
#define WS_PDT   6144                     // per-WG probe data slots (256 x 64B)
#define WS_H     24576                    // h_shared [Bn][KSn] bf16 (cols 512..516 = x_t, rest 0)
#define WS_HL    (WS_H   + Bn*KSn*2)      // hlstm    [Bn][KSn] bf16
#define WS_FEAT  (WS_HL  + Bn*KSn*2)      // feat     [Bn][BBn] bf16
#define WS_WH    (WS_FEAT + Bn*BBn*2)     // Wh_ext   [2048][KSn] bf16 (k>=512 -> Wi, pad 0)
#define WS_BB    (WS_WH  + 2048*KSn*2)    // bb_ext   [128][KSn] bf16
#define WS_FF    (WS_BB  + 128*KSn*2)     // ff       [4][Hn][BBn] bf16

// ---- dynamic LDS layout (bytes) ----
#define LB_A     0                        // activation stage: 32*KSP*2 = 35328 (reused: h / hlstm / feat)
#define LB_WH    (LB_A + 32*KSP*2)        // Wh slice: [4 gates][16 cols][KSP] = 70656
#define LB_FF    (LB_WH + 64*KSP*2)       // ff slice: [4 mats][16 cols][BBP] = 17408
#define DYN_LDS  (LB_FF + 64*BBP*2)       // = 123392 B (+9216 static lbuf = 132608 <= 160K)

// ---- d_out layout (floats) ----
#define YO 0
#define EO (Bn*Tn*2)
#define HO (EO + Bn*Tn)
#define CO (HO + Bn*Hn)

__device__ __forceinline__ unsigned short f2bf(float f) {
  union { float f; unsigned u; } v; v.f = f;
  unsigned r = v.u + 0x7FFFu + ((v.u >> 16) & 1u);
  return (unsigned short)(r >> 16);
}
__device__ __forceinline__ float bf2f(unsigned short u) {
  union { unsigned u; float f; } v; v.u = ((unsigned)u) << 16;
  return v.f;
}
__device__ __forceinline__ float sigm(float x) { return 1.f / (1.f + __expf(-x)); }
__device__ __forceinline__ float tanhx(float x) {
  float e = __expf(2.f * x);
  return 1.f - 2.f / (e + 1.f);
}

// Agent-scope relaxed atomic loads: the compiler emits the architecturally-correct
// L1-coherent encoding (same primitive as the proven slow-path spin). This replaces
// plain-load + manual buffer_inv, whose flag semantics we guessed wrong twice
// (round 5/6: probe round-2 caught stale L1 -> fallback every time).
__device__ __forceinline__ u64 ldq_agent(const void* p) {
  return __hip_atomic_load((const u64*)p, __ATOMIC_RELAXED, __HIP_MEMORY_SCOPE_AGENT);
}
__device__ __forceinline__ int ldi_agent(const void* p) {
  return __hip_atomic_load((const int*)p, __ATOMIC_RELAXED, __HIP_MEMORY_SCOPE_AGENT);
}

// L2-point atomics (no sc1 -> executed in the XCD-shared L2, not the LLC).
// Spin must be a real RMW (sc0, returned old): proven working rounds 4-6.
__device__ __forceinline__ void l2_add_nr(int* p, int v) {
  asm volatile("global_atomic_add %0, %1, off" :: "v"(p), "v"(v) : "memory");
}
__device__ __forceinline__ int l2_add_ret(int* p, int v) {
  int old;
  asm volatile("global_atomic_add %0, %1, %2, off sc0\n\t"
               "s_waitcnt vmcnt(0)"
               : "=v"(old) : "v"(p), "v"(v) : "memory");
  return old;
}

// ---------------- weight prep: f32 -> bf16, padded/extended layouts ----------------
__global__ void __launch_bounds__(256) prep_weights(
    const float* __restrict__ Wh, const float* __restrict__ Wi, const float* __restrict__ bbW,
    const float* __restrict__ f1W, const float* __restrict__ f2W,
    const float* __restrict__ taW, const float* __restrict__ tbW, char* __restrict__ ws)
{
  unsigned short* wh = (unsigned short*)(ws + WS_WH);
  unsigned short* bb = (unsigned short*)(ws + WS_BB);
  unsigned short* ff = (unsigned short*)(ws + WS_FF);
  const int n1 = 2048 * KSn, n2 = 128 * KSn, n3 = Hn * BBn;
  const int ntot = n1 + n2 + 4 * n3;
  for (int i = blockIdx.x * blockDim.x + threadIdx.x; i < ntot; i += gridDim.x * blockDim.x) {
    if (i < n1) {
      int c = i / KSn, k = i % KSn;
      float v = (k < 512) ? Wh[c * 512 + k] : ((k < 517) ? Wi[c * 5 + (k - 512)] : 0.f);
      wh[i] = f2bf(v);
    } else if (i < n1 + n2) {
      int j = i - n1; int o = j / KSn, k = j % KSn;
      float v = (k < 512) ? bbW[o * 517 + 5 + k] : ((k < 517) ? bbW[o * 517 + (k - 512)] : 0.f);
      bb[j] = f2bf(v);
    } else {
      int j = i - n1 - n2; int m = j / n3; int r = j % n3;
      const float* src = (m == 0) ? f1W : (m == 1) ? f2W : (m == 2) ? taW : tbW;
      ff[j] = f2bf(src[r]);
    }
  }
}

// ---------------- barriers ----------------
// FAST (probe-validated same-XCD cluster): syncthreads drains stores to the shared XCD
// L2 (proven: slow path's wbl2 flushes correct data); tid0 L2-point RMW inc + spin;
// releasing syncthreads. NO cache maintenance — consumers read via agent atomic loads.
// SLOW (fallback): device-scope threadfence protocol — the round-2 proven path.
__device__ __forceinline__ void cluster_bar(int* ctr, int target, bool fast) {
  __syncthreads();
  if (threadIdx.x == 0) {
    if (fast) {
      l2_add_nr(ctr, 1);
      int tries = 0;
      while (l2_add_ret(ctr, 0) < target) {
        __builtin_amdgcn_s_sleep(1);
        if (++tries >= (1 << 18)) break;   // watchdog: degrade diagnosably, never hang
      }
    } else {
      __threadfence();
      atomicAdd(ctr, 1);
      int tries = 0;
      while (__hip_atomic_load(ctr, __ATOMIC_RELAXED, __HIP_MEMORY_SCOPE_AGENT) < target) {
        __builtin_amdgcn_s_sleep(2);
        if (++tries >= (1 << 18)) break;
      }
      __threadfence();
    }
  }
  __syncthreads();
}

// ---------------- main persistent scan kernel ----------------
__global__ void __launch_bounds__(256, 1) ebl_main(
    const float* __restrict__ x,   const float* __restrict__ bi,
    const float* __restrict__ bbb, const float* __restrict__ f1b, const float* __restrict__ f2b,
    const float* __restrict__ tab, const float* __restrict__ tbb,
    const float* __restrict__ predW, const float* __restrict__ predb,
    const float* __restrict__ enW,   const float* __restrict__ enb,
    float* __restrict__ out, char* __restrict__ ws)
{
  extern __shared__ char lds[];
  __shared__ float lbuf[4][16][36];       // [gate/matrix][col][row(padded)] f32
  __shared__ int   pflag;

  unsigned short* hsh = (unsigned short*)(ws + WS_H);
  unsigned short* hls = (unsigned short*)(ws + WS_HL);
  unsigned short* fsh = (unsigned short*)(ws + WS_FEAT);
  const unsigned short* wh  = (const unsigned short*)(ws + WS_WH);
  const unsigned short* bbw = (const unsigned short*)(ws + WS_BB);
  const unsigned short* ffw = (const unsigned short*)(ws + WS_FF);

  const int tid  = threadIdx.x;
  const int lane = tid & 63;
  const int wv   = tid >> 6;              // wave 0..3 = gate / ff-matrix index
  const int cl   = blockIdx.x & 7;        // cluster
  const int wg   = blockIdx.x >> 3;       // 0..31 within cluster
  const int rbase = cl * WPC;             // batch-row base of cluster
  const int jbase = wg * 16;              // hidden-column slice of this WG

  int* cctr = (int*)(ws + WS_BAR) + cl * 32;   // per-cluster main counter
  int* pctr = (int*)(ws + WS_PRB) + cl * 32;   // per-cluster probe counter
  int* dctr = (int*)(ws + WS_DC);              // device startup barrier
  int* xccb = (int*)(ws + WS_XCC);             // per-WG XCC ids
  int* pokb = (int*)(ws + WS_POK);             // per-WG probe verdicts
  int* pdat = (int*)(ws + WS_PDT);             // per-WG probe data slots (stride 16 ints)

  const int l15 = lane & 15;
  const int l4  = lane >> 4;
  const int cc  = tid & 15;               // combine-phase column
  const int rr  = tid >> 4;               // combine-phase row

  // ---- one-time LDS weight residency: Wh slice (64 rows x 544) + ff slice (64 rows x 128) ----
  for (int idx = tid; idx < 64 * 68; idx += 256) {
    int r = idx / 68, ch = idx - r * 68;   // r = g*16 + c
    int g = r >> 4, c = r & 15;
    bf16x8 v = *(const bf16x8*)(wh + (g * 512 + jbase + c) * KSn + ch * 8);
    *(bf16x8*)(lds + LB_WH + r * (KSP * 2) + ch * 16) = v;
  }
  for (int idx = tid; idx < 64 * 16; idx += 256) {
    int r = idx >> 4, ch = idx & 15;       // r = m*16 + c
    int m = r >> 4, c = r & 15;
    bf16x8 v = *(const bf16x8*)(ffw + m * (Hn * BBn) + (jbase + c) * BBn + ch * 8);
    *(bf16x8*)(lds + LB_FF + r * (BBP * 2) + ch * 16) = v;
  }

  // ---- stationary per-thread preloads ----
  float hp0[8], hp1[8], hpe[8];
  if (wv == 0) {
    #pragma unroll
    for (int j = 0; j < 8; ++j) {
      hp0[j] = predW[lane * 8 + j];
      hp1[j] = predW[512 + lane * 8 + j];
      hpe[j] = enW[lane * 8 + j];
    }
  }
  float biC[4];
  #pragma unroll
  for (int g = 0; g < 4; ++g) biC[g] = bi[g * 512 + jbase + cc];
  const float fb1 = f1b[jbase + cc], fb2v = f2b[jbase + cc];
  const float fta = tab[jbase + cc], ftb = tbb[jbase + cc];
  const float bbB = (wg < 8) ? bbb[wg * 16 + l15] : 0.f;

  float cst0 = 0.f, cst1 = 0.f;

  // ---- startup: publish XCC id, x_0; device barrier; XCD-uniformity verdict ----
  int xcc;
  asm volatile("s_getreg_b32 %0, hwreg(HW_REG_XCC_ID)" : "=s"(xcc));
  if (tid == 0) { xccb[blockIdx.x] = xcc; pflag = 1; }
  if (tid < Fn) {
    int b = rbase + wg;
    hsh[b * KSn + 512 + tid] = f2bf(x[(b * Tn + 0) * Fn + tid]);
  }
  cluster_bar(dctr, NWG, false);          // device-scope, full fences

  int refx = xccb[cl];
  int vx   = xccb[cl + 8 * (tid & 31)];
  const bool fast = (__ballot(vx != refx) == 0ull);

  // ---- probe: full DATA propagation through the fast mechanism, twice, ALL waves ----
  // Round 1: store -> fast-bar -> agent-load remote read. Round 2: rewrite + second
  // fast-bar re-read (catches any residual caching of the agent-load path — the round
  // 5/6 failure mode). Any failure -> slow fallback (round-2 proven).
  if (fast) {
    if (tid == 0) pdat[blockIdx.x * 16] = 1000 + blockIdx.x;
    cluster_bar(pctr, WPC, true);
    {
      int g = cl + 8 * (tid & 31);
      if (ldi_agent(&pdat[g * 16]) != 1000 + g) pflag = 0;
    }
    __syncthreads();
    if (tid == 0) pdat[blockIdx.x * 16] = 777000 + blockIdx.x * 3;
    cluster_bar(pctr, 2 * WPC, true);
    {
      int g = cl + 8 * (tid & 31);
      if (ldi_agent(&pdat[g * 16]) != 777000 + g * 3) pflag = 0;
    }
    __syncthreads();
    if (tid == 0) pokb[blockIdx.x] = pflag;
    __syncthreads();
  }
  cluster_bar(dctr, 2 * NWG, false);      // device-scope: publish pokb

  int pv = pokb[cl + 8 * (tid & 31)];
  const bool fastrun = fast && (__ballot(pv == 0) == 0ull);

  int phase = 0;
  for (int t = 0; t < Tn; ++t) {
    // ---------- fused heads for step t-1 (wave 0; hsh holds h after step t-1) ----------
    if (wv == 0 && t > 0) {
      const int b = rbase + wg;
      u64 q0 = ldq_agent((const char*)hsh + b * (KSn * 2) + lane * 16);
      u64 q1 = ldq_agent((const char*)hsh + b * (KSn * 2) + lane * 16 + 8);
      float s0 = 0.f, s1 = 0.f, se = 0.f;
      #pragma unroll
      for (int j = 0; j < 8; ++j) {
        unsigned short us = (unsigned short)(((j < 4) ? q0 : q1) >> (16 * (j & 3)));
        float hv = bf2f(us);
        s0 += hv * hp0[j]; s1 += hv * hp1[j]; se += hv * hpe[j];
      }
      #pragma unroll
      for (int off = 32; off > 0; off >>= 1) {
        s0 += __shfl_down(s0, off);
        s1 += __shfl_down(s1, off);
        se += __shfl_down(se, off);
      }
      if (lane == 0) {
        out[YO + b * (Tn * 2) + (t - 1) * 2 + 0] = s0 + predb[0];
        out[YO + b * (Tn * 2) + (t - 1) * 2 + 1] = s1 + predb[1];
        out[EO + b * Tn + (t - 1)]               = se + enb[0];
      }
    }
    // x_t into hlstm ext cols (consumed by stage B after bar1)
    if (tid < Fn) {
      int b = rbase + wg;
      hls[b * KSn + 512 + tid] = f2bf(x[(b * Tn + t) * Fn + tid]);
    }

    // ---------- stage A: stage h -> LDS (agent loads); z = [h,x_t] @ Wh^T; gates ----------
    for (int idx = tid; idx < 32 * 136; idx += 256) {          // row = 544 shorts = 136 qwords
      int r = idx / 136, ch = idx - r * 136;
      u64 v = ldq_agent((const char*)hsh + (rbase + r) * (KSn * 2) + ch * 8);
      *(u64*)(lds + LB_A + r * (KSP * 2) + ch * 8) = v;
    }
    __syncthreads();
    {
      f32x4 acc0 = {0.f, 0.f, 0.f, 0.f}, acc1 = {0.f, 0.f, 0.f, 0.f};
      const char* a0b = lds + LB_A + l15 * (KSP * 2) + l4 * 16;
      const char* a1b = a0b + 16 * (KSP * 2);
      const char* wb  = lds + LB_WH + (wv * 16 + l15) * (KSP * 2) + l4 * 16;
      #pragma unroll
      for (int ks = 0; ks < 17; ++ks) {
        bf16x8 a0 = *(const bf16x8*)(a0b + ks * 64);
        bf16x8 a1 = *(const bf16x8*)(a1b + ks * 64);
        bf16x8 b8 = *(const bf16x8*)(wb + ks * 64);
        acc0 = __builtin_amdgcn_mfma_f32_16x16x32_bf16(a0, b8, acc0, 0, 0, 0);
        acc1 = __builtin_amdgcn_mfma_f32_16x16x32_bf16(a1, b8, acc1, 0, 0, 0);
      }
      *(f32x4*)(&lbuf[wv][l15][l4 * 4])      = acc0;
      *(f32x4*)(&lbuf[wv][l15][16 + l4 * 4]) = acc1;
    }
    __syncthreads();
    {
      float zi0 = lbuf[0][cc][rr]      + biC[0];
      float zg0 = lbuf[1][cc][rr]      + biC[1];
      float zf0 = lbuf[2][cc][rr]      + biC[2];
      float zo0 = lbuf[3][cc][rr]      + biC[3];
      float zi1 = lbuf[0][cc][rr + 16] + biC[0];
      float zg1 = lbuf[1][cc][rr + 16] + biC[1];
      float zf1 = lbuf[2][cc][rr + 16] + biC[2];
      float zo1 = lbuf[3][cc][rr + 16] + biC[3];
      float cn0 = cst0 * sigm(zf0 + 1.f) + tanhx(zi0) * sigm(zg0);
      float cn1 = cst1 * sigm(zf1 + 1.f) + tanhx(zi1) * sigm(zg1);
      float hl0 = tanhx(cn0) * sigm(zo0);
      float hl1 = tanhx(cn1) * sigm(zo1);
      cst0 = cn0; cst1 = cn1;
      const int b0 = rbase + rr, b1 = rbase + rr + 16;
      hls[b0 * KSn + jbase + cc] = f2bf(hl0);
      hls[b1 * KSn + jbase + cc] = f2bf(hl1);
      if (t == Tn - 1) {
        out[CO + b0 * Hn + jbase + cc] = cn0;
        out[CO + b1 * Hn + jbase + cc] = cn1;
      }
    }
    ++phase; cluster_bar(cctr, phase * WPC, fastrun);

    // ---------- stage B: feat = lecun_tanh([h_lstm,x_t] @ bb^T) (WGs 0..7) ----------
    if (wg < 8) {
      for (int idx = tid; idx < 32 * 136; idx += 256) {
        int r = idx / 136, ch = idx - r * 136;
        u64 v = ldq_agent((const char*)hls + (rbase + r) * (KSn * 2) + ch * 8);
        *(u64*)(lds + LB_A + r * (KSP * 2) + ch * 8) = v;
      }
      __syncthreads();
      if (wv < 2) {
        f32x4 accB = {0.f, 0.f, 0.f, 0.f};
        const char* ab = lds + LB_A + (wv * 16 + l15) * (KSP * 2) + l4 * 16;
        const unsigned short* brow = bbw + (wg * 16 + l15) * KSn + l4 * 8;
        #pragma unroll
        for (int ks = 0; ks < 17; ++ks) {
          bf16x8 a  = *(const bf16x8*)(ab + ks * 64);
          bf16x8 b8 = *(const bf16x8*)(brow + ks * 32);
          accB = __builtin_amdgcn_mfma_f32_16x16x32_bf16(a, b8, accB, 0, 0, 0);
        }
        #pragma unroll
        for (int j = 0; j < 4; ++j) {
          float v = accB[j] + bbB;
          v = 1.7159f * tanhx(0.666f * v);
          int b = rbase + wv * 16 + l4 * 4 + j;
          fsh[b * BBn + wg * 16 + l15] = f2bf(v);
        }
      }
    }
    ++phase; cluster_bar(cctr, phase * WPC, fastrun);

    // ---------- stage C: stage feat -> LDS (agent loads); ff1/ff2/ta/tb; h_new ----------
    for (int idx = tid; idx < 32 * 32; idx += 256) {           // row = 128 shorts = 32 qwords
      int r = idx >> 5, ch = idx & 31;
      u64 v = ldq_agent((const char*)fsh + (rbase + r) * (BBn * 2) + ch * 8);
      *(u64*)(lds + LB_A + r * (BBP * 2) + ch * 8) = v;
    }
    __syncthreads();
    {
      f32x4 ac0 = {0.f, 0.f, 0.f, 0.f}, ac1 = {0.f, 0.f, 0.f, 0.f};
      const char* a0b = lds + LB_A + l15 * (BBP * 2) + l4 * 16;
      const char* a1b = a0b + 16 * (BBP * 2);
      const char* wb  = lds + LB_FF + (wv * 16 + l15) * (BBP * 2) + l4 * 16;
      #pragma unroll
      for (int ks = 0; ks < 4; ++ks) {
        bf16x8 a0 = *(const bf16x8*)(a0b + ks * 64);
        bf16x8 a1 = *(const bf16x8*)(a1b + ks * 64);
        bf16x8 b8 = *(const bf16x8*)(wb + ks * 64);
        ac0 = __builtin_amdgcn_mfma_f32_16x16x32_bf16(a0, b8, ac0, 0, 0, 0);
        ac1 = __builtin_amdgcn_mfma_f32_16x16x32_bf16(a1, b8, ac1, 0, 0, 0);
      }
      *(f32x4*)(&lbuf[wv][l15][l4 * 4])      = ac0;
      *(f32x4*)(&lbuf[wv][l15][16 + l4 * 4]) = ac1;
    }
    __syncthreads();
    {
      float p10 = lbuf[0][cc][rr] + fb1,      p20 = lbuf[1][cc][rr] + fb2v;
      float pa0 = lbuf[2][cc][rr] + fta,      pb0 = lbuf[3][cc][rr] + ftb;
      float p11 = lbuf[0][cc][rr + 16] + fb1, p21 = lbuf[1][cc][rr + 16] + fb2v;
      float pa1 = lbuf[2][cc][rr + 16] + fta, pb1 = lbuf[3][cc][rr + 16] + ftb;
      float f10 = tanhx(p10), f20 = tanhx(p20), ti0 = sigm(pa0 + pb0);
      float f11 = tanhx(p11), f21 = tanhx(p21), ti1 = sigm(pa1 + pb1);
      float hn0 = f10 + ti0 * (f20 - f10);
      float hn1 = f11 + ti1 * (f21 - f11);
      const int b0 = rbase + rr, b1 = rbase + rr + 16;
      hsh[b0 * KSn + jbase + cc] = f2bf(hn0);
      hsh[b1 * KSn + jbase + cc] = f2bf(hn1);
      if (t == Tn - 1) {
        out[HO + b0 * Hn + jbase + cc] = hn0;
        out[HO + b1 * Hn + jbase + cc] = hn1;
      }
    }
    if (t + 1 < Tn && tid < Fn) {
      int b = rbase + wg;
      hsh[b * KSn + 512 + tid] = f2bf(x[(b * Tn + t + 1) * Fn + tid]);
    }
    ++phase; cluster_bar(cctr, phase * WPC, fastrun);
  }

  // ---------- epilogue heads for t = Tn-1 ----------
  if (wv == 0) {
    const int b = rbase + wg;
    u64 q0 = ldq_agent((const char*)hsh + b * (KSn * 2) + lane * 16);
    u64 q1 = ldq_agent((const char*)hsh + b * (KSn * 2) + lane * 16 + 8);
    float s0 = 0.f, s1 = 0.f, se = 0.f;
    #pragma unroll
    for (int j = 0; j < 8; ++j) {
      unsigned short us = (unsigned short)(((j < 4) ? q0 : q1) >> (16 * (j & 3)));
      float hv = bf2f(us);
      s0 += hv * hp0[j]; s1 += hv * hp1[j]; se += hv * hpe[j];
    }
    #pragma unroll
    for (int off = 32; off > 0; off >>= 1) {
      s0 += __shfl_down(s0, off);
      s1 += __shfl_down(s1, off);
      se += __shfl_down(se, off);
    }
    if (lane == 0) {
      out[YO + b * (Tn * 2) + (Tn - 1) * 2 + 0] = s0 + predb[0];
      out[YO + b * (Tn * 2) + (Tn - 1) * 2 + 1] = s1 + predb[1];
      out[EO + b * Tn + (Tn - 1)]               = se + enb[0];
    }
  }
}

extern "C" void kernel_launch(void* const* d_in, const int* in_sizes, int n_in,
                              void* d_out, int out_size, void* d_ws, size_t ws_size,
                              hipStream_t stream) {
  const float* x   = (const float*)d_in[0];
  const float* Wi  = (const float*)d_in[1];
  const float* bi  = (const float*)d_in[2];
  const float* Wh  = (const float*)d_in[3];
  const float* bbW = (const float*)d_in[4];
  const float* bbb = (const float*)d_in[5];
  const float* f1W = (const float*)d_in[6];
  const float* f1b = (const float*)d_in[7];
  const float* f2W = (const float*)d_in[8];
  const float* f2b = (const float*)d_in[9];
  const float* taW = (const float*)d_in[10];
  const float* tab = (const float*)d_in[11];
  const float* tbW = (const float*)d_in[12];
  const float* tbb = (const float*)d_in[13];
  const float* pW  = (const float*)d_in[14];
  const float* pb  = (const float*)d_in[15];
  const float* eW  = (const float*)d_in[16];
  const float* eb  = (const float*)d_in[17];
  float* out = (float*)d_out;
  char* ws = (char*)d_ws;

  static_assert(DYN_LDS == 123392, "LDS layout");
  (void)hipFuncSetAttribute((const void*)ebl_main,
                            hipFuncAttributeMaxDynamicSharedMemorySize, DYN_LDS);

  // zero barriers + verdict/probe tables + activation buffers (replayed every launch)
  hipMemsetAsync(ws, 0, WS_WH, stream);
  prep_weights<<<2048, 256, 0, stream>>>(Wh, Wi, bbW, f1W, f2W, taW, tbW, ws);

  void* args[] = { (void*)&x, (void*)&bi, (void*)&bbb, (void*)&f1b, (void*)&f2b,
                   (void*)&tab, (void*)&tbb, (void*)&pW, (void*)&pb, (void*)&eW,
                   (void*)&eb, (void*)&out, (void*)&ws };
  hipLaunchCooperativeKernel((const void*)ebl_main, dim3(NWG), dim3(256), args,
                             DYN_LDS, stream);
}

// Round 8
// 8864.314 us; speedup vs baseline: 2.5753x; 1.0429x over previous
//
#include <hip/hip_runtime.h>

// ---- problem dims ----
#define Bn   256
#define Tn   512
#define Fn   5
#define Hn   512
#define BBn  128
#define KSn  544          // 512 (H) + 5 (x) + pad to 17*32
#define KSP  552          // LDS row stride (shorts) for 544-col tiles: +8 -> 2-way banks only
#define BBP  136          // LDS row stride (shorts) for 128-col tiles
#define NC   8            // clusters (XCD round-robin by blockIdx%8 — verified at runtime, not assumed)
#define WPC  32           // workgroups per cluster
#define NWG  (NC*WPC)

typedef __attribute__((ext_vector_type(8))) short bf16x8;
typedef __attribute__((ext_vector_type(4))) float f32x4;
typedef unsigned long long u64;

// ---- d_ws layout (bytes) ----
#define WS_BAR   0                        // per-cluster main counters, 128B apart (8 x 128B)
#define WS_PRB   1024                     // per-cluster probe counters, 128B apart
#define WS_DC    2048                     // device-wide startup barrier counter
#define WS_XCC   4096                     // per-WG XCC id table (256 ints)
#define WS_POK   5120                     // per-WG probe-ok table (256 ints)
#define WS_PDT   6144                     // per-WG probe data slots (256 x 64B)
#define WS_H     24576                    // h_shared [Bn][KSn] bf16 (cols 512..516 = x_t, rest 0)
#define WS_HL    (WS_H   + Bn*KSn*2)      // hlstm    [Bn][KSn] bf16
#define WS_FEAT  (WS_HL  + Bn*KSn*2)      // feat     [Bn][BBn] bf16
#define WS_WH    (WS_FEAT + Bn*BBn*2)     // Wh_ext   [2048][KSn] bf16 (k>=512 -> Wi, pad 0)
#define WS_BB    (WS_WH  + 2048*KSn*2)    // bb_ext   [128][KSn] bf16
#define WS_FF    (WS_BB  + 128*KSn*2)     // ff       [4][Hn][BBn] bf16

// ---- dynamic LDS layout (bytes) ----
#define LB_A     0                        // activation stage: 32*KSP*2 = 35328 (reused: h / hlstm / feat)
#define LB_WH    (LB_A + 32*KSP*2)        // Wh slice: [4 gates][16 cols][KSP] = 70656
#define LB_FF    (LB_WH + 64*KSP*2)       // ff slice: [4 mats][16 cols][BBP] = 17408
#define DYN_LDS  (LB_FF + 64*BBP*2)       // = 123392 B (+9216 static lbuf = 132608 <= 160K)

// ---- d_out layout (floats) ----
#define YO 0
#define EO (Bn*Tn*2)
#define HO (EO + Bn*Tn)
#define CO (HO + Bn*Hn)

__device__ __forceinline__ unsigned short f2bf(float f) {
  union { float f; unsigned u; } v; v.f = f;
  unsigned r = v.u + 0x7FFFu + ((v.u >> 16) & 1u);
  return (unsigned short)(r >> 16);
}
__device__ __forceinline__ float bf2f(unsigned short u) {
  union { unsigned u; float f; } v; v.u = ((unsigned)u) << 16;
  return v.f;
}
__device__ __forceinline__ float sigm(float x) { return 1.f / (1.f + __expf(-x)); }
__device__ __forceinline__ float tanhx(float x) {
  float e = __expf(2.f * x);
  return 1.f - 2.f / (e + 1.f);
}

// Agent-scope relaxed atomic loads: L1-bypassing, served by the XCD L2 (validated by
// this round's probe + 9.2ms pass). Round-7 lesson: load->ds_write in ONE loop emits
// waitcnt vmcnt(0) per iteration (17 serialized L2 round trips ~= 4.2us/stage). The
// staging below is therefore hand-pipelined: all loads into a statically-indexed reg
// array first (17 outstanding), then the LDS writes (incremental vmcnt waits).
__device__ __forceinline__ u64 ldq_agent(const void* p) {
  return __hip_atomic_load((const u64*)p, __ATOMIC_RELAXED, __HIP_MEMORY_SCOPE_AGENT);
}
__device__ __forceinline__ int ldi_agent(const void* p) {
  return __hip_atomic_load((const int*)p, __ATOMIC_RELAXED, __HIP_MEMORY_SCOPE_AGENT);
}

// L2-point atomics (no sc1 -> executed in the XCD-shared L2, not the LLC).
__device__ __forceinline__ void l2_add_nr(int* p, int v) {
  asm volatile("global_atomic_add %0, %1, off" :: "v"(p), "v"(v) : "memory");
}
__device__ __forceinline__ int l2_add_ret(int* p, int v) {
  int old;
  asm volatile("global_atomic_add %0, %1, %2, off sc0\n\t"
               "s_waitcnt vmcnt(0)"
               : "=v"(old) : "v"(p), "v"(v) : "memory");
  return old;
}

// ---------------- weight prep: f32 -> bf16, padded/extended layouts ----------------
__global__ void __launch_bounds__(256) prep_weights(
    const float* __restrict__ Wh, const float* __restrict__ Wi, const float* __restrict__ bbW,
    const float* __restrict__ f1W, const float* __restrict__ f2W,
    const float* __restrict__ taW, const float* __restrict__ tbW, char* __restrict__ ws)
{
  unsigned short* wh = (unsigned short*)(ws + WS_WH);
  unsigned short* bb = (unsigned short*)(ws + WS_BB);
  unsigned short* ff = (unsigned short*)(ws + WS_FF);
  const int n1 = 2048 * KSn, n2 = 128 * KSn, n3 = Hn * BBn;
  const int ntot = n1 + n2 + 4 * n3;
  for (int i = blockIdx.x * blockDim.x + threadIdx.x; i < ntot; i += gridDim.x * blockDim.x) {
    if (i < n1) {
      int c = i / KSn, k = i % KSn;
      float v = (k < 512) ? Wh[c * 512 + k] : ((k < 517) ? Wi[c * 5 + (k - 512)] : 0.f);
      wh[i] = f2bf(v);
    } else if (i < n1 + n2) {
      int j = i - n1; int o = j / KSn, k = j % KSn;
      float v = (k < 512) ? bbW[o * 517 + 5 + k] : ((k < 517) ? bbW[o * 517 + (k - 512)] : 0.f);
      bb[j] = f2bf(v);
    } else {
      int j = i - n1 - n2; int m = j / n3; int r = j % n3;
      const float* src = (m == 0) ? f1W : (m == 1) ? f2W : (m == 2) ? taW : tbW;
      ff[j] = f2bf(src[r]);
    }
  }
}

// ---------------- barriers ----------------
// FAST (probe-validated same-XCD cluster): syncthreads drains stores to the shared XCD
// L2; tid0 L2-point RMW inc + spin; releasing syncthreads. Consumers read via agent
// loads — no cache maintenance needed (proven round 7).
// SLOW (fallback): device-scope threadfence protocol — the round-2 proven path.
__device__ __forceinline__ void cluster_bar(int* ctr, int target, bool fast) {
  __syncthreads();
  if (threadIdx.x == 0) {
    if (fast) {
      l2_add_nr(ctr, 1);
      int tries = 0;
      while (l2_add_ret(ctr, 0) < target) {
        if (++tries >= (1 << 18)) break;   // watchdog: degrade diagnosably, never hang
        __builtin_amdgcn_s_sleep(1);
      }
    } else {
      __threadfence();
      atomicAdd(ctr, 1);
      int tries = 0;
      while (__hip_atomic_load(ctr, __ATOMIC_RELAXED, __HIP_MEMORY_SCOPE_AGENT) < target) {
        __builtin_amdgcn_s_sleep(2);
        if (++tries >= (1 << 18)) break;
      }
      __threadfence();
    }
  }
  __syncthreads();
}

// ---------------- main persistent scan kernel ----------------
__global__ void __launch_bounds__(256, 1) ebl_main(
    const float* __restrict__ x,   const float* __restrict__ bi,
    const float* __restrict__ bbb, const float* __restrict__ f1b, const float* __restrict__ f2b,
    const float* __restrict__ tab, const float* __restrict__ tbb,
    const float* __restrict__ predW, const float* __restrict__ predb,
    const float* __restrict__ enW,   const float* __restrict__ enb,
    float* __restrict__ out, char* __restrict__ ws)
{
  extern __shared__ char lds[];
  __shared__ float lbuf[4][16][36];       // [gate/matrix][col][row(padded)] f32
  __shared__ int   pflag;

  unsigned short* hsh = (unsigned short*)(ws + WS_H);
  unsigned short* hls = (unsigned short*)(ws + WS_HL);
  unsigned short* fsh = (unsigned short*)(ws + WS_FEAT);
  const unsigned short* wh  = (const unsigned short*)(ws + WS_WH);
  const unsigned short* bbw = (const unsigned short*)(ws + WS_BB);
  const unsigned short* ffw = (const unsigned short*)(ws + WS_FF);

  const int tid  = threadIdx.x;
  const int lane = tid & 63;
  const int wv   = tid >> 6;              // wave 0..3 = gate / ff-matrix index
  const int cl   = blockIdx.x & 7;        // cluster
  const int wg   = blockIdx.x >> 3;       // 0..31 within cluster
  const int rbase = cl * WPC;             // batch-row base of cluster
  const int jbase = wg * 16;              // hidden-column slice of this WG

  int* cctr = (int*)(ws + WS_BAR) + cl * 32;   // per-cluster main counter
  int* pctr = (int*)(ws + WS_PRB) + cl * 32;   // per-cluster probe counter
  int* dctr = (int*)(ws + WS_DC);              // device startup barrier
  int* xccb = (int*)(ws + WS_XCC);             // per-WG XCC ids
  int* pokb = (int*)(ws + WS_POK);             // per-WG probe verdicts
  int* pdat = (int*)(ws + WS_PDT);             // per-WG probe data slots (stride 16 ints)

  const int l15 = lane & 15;
  const int l4  = lane >> 4;
  const int cc  = tid & 15;               // combine-phase column
  const int rr  = tid >> 4;               // combine-phase row

  // ---- one-time LDS weight residency: Wh slice (64 rows x 544) + ff slice (64 rows x 128) ----
  for (int idx = tid; idx < 64 * 68; idx += 256) {
    int r = idx / 68, ch = idx - r * 68;   // r = g*16 + c
    int g = r >> 4, c = r & 15;
    bf16x8 v = *(const bf16x8*)(wh + (g * 512 + jbase + c) * KSn + ch * 8);
    *(bf16x8*)(lds + LB_WH + r * (KSP * 2) + ch * 16) = v;
  }
  for (int idx = tid; idx < 64 * 16; idx += 256) {
    int r = idx >> 4, ch = idx & 15;       // r = m*16 + c
    int m = r >> 4, c = r & 15;
    bf16x8 v = *(const bf16x8*)(ffw + m * (Hn * BBn) + (jbase + c) * BBn + ch * 8);
    *(bf16x8*)(lds + LB_FF + r * (BBP * 2) + ch * 16) = v;
  }

  // ---- stationary per-thread preloads ----
  float hp0[8], hp1[8], hpe[8];
  if (wv == 0) {
    #pragma unroll
    for (int j = 0; j < 8; ++j) {
      hp0[j] = predW[lane * 8 + j];
      hp1[j] = predW[512 + lane * 8 + j];
      hpe[j] = enW[lane * 8 + j];
    }
  }
  float biC[4];
  #pragma unroll
  for (int g = 0; g < 4; ++g) biC[g] = bi[g * 512 + jbase + cc];
  const float fb1 = f1b[jbase + cc], fb2v = f2b[jbase + cc];
  const float fta = tab[jbase + cc], ftb = tbb[jbase + cc];
  const float bbB = (wg < 8) ? bbb[wg * 16 + l15] : 0.f;

  float cst0 = 0.f, cst1 = 0.f;

  // ---- startup: publish XCC id, x_0; device barrier; XCD-uniformity verdict ----
  int xcc;
  asm volatile("s_getreg_b32 %0, hwreg(HW_REG_XCC_ID)" : "=s"(xcc));
  if (tid == 0) { xccb[blockIdx.x] = xcc; pflag = 1; }
  if (tid < Fn) {
    int b = rbase + wg;
    hsh[b * KSn + 512 + tid] = f2bf(x[(b * Tn + 0) * Fn + tid]);
  }
  cluster_bar(dctr, NWG, false);          // device-scope, full fences

  int refx = xccb[cl];
  int vx   = xccb[cl + 8 * (tid & 31)];
  const bool fast = (__ballot(vx != refx) == 0ull);

  // ---- probe: full DATA propagation through the fast mechanism, twice, ALL waves ----
  if (fast) {
    if (tid == 0) pdat[blockIdx.x * 16] = 1000 + blockIdx.x;
    cluster_bar(pctr, WPC, true);
    {
      int g = cl + 8 * (tid & 31);
      if (ldi_agent(&pdat[g * 16]) != 1000 + g) pflag = 0;
    }
    __syncthreads();
    if (tid == 0) pdat[blockIdx.x * 16] = 777000 + blockIdx.x * 3;
    cluster_bar(pctr, 2 * WPC, true);
    {
      int g = cl + 8 * (tid & 31);
      if (ldi_agent(&pdat[g * 16]) != 777000 + g * 3) pflag = 0;
    }
    __syncthreads();
    if (tid == 0) pokb[blockIdx.x] = pflag;
    __syncthreads();
  }
  cluster_bar(dctr, 2 * NWG, false);      // device-scope: publish pokb

  int pv = pokb[cl + 8 * (tid & 31)];
  const bool fastrun = fast && (__ballot(pv == 0) == 0ull);

  int phase = 0;
  for (int t = 0; t < Tn; ++t) {
    // ---------- fused heads for step t-1 (wave 0; hsh holds h after step t-1) ----------
    if (wv == 0 && t > 0) {
      const int b = rbase + wg;
      u64 q0 = ldq_agent((const char*)hsh + b * (KSn * 2) + lane * 16);
      u64 q1 = ldq_agent((const char*)hsh + b * (KSn * 2) + lane * 16 + 8);
      float s0 = 0.f, s1 = 0.f, se = 0.f;
      #pragma unroll
      for (int j = 0; j < 8; ++j) {
        unsigned short us = (unsigned short)(((j < 4) ? q0 : q1) >> (16 * (j & 3)));
        float hv = bf2f(us);
        s0 += hv * hp0[j]; s1 += hv * hp1[j]; se += hv * hpe[j];
      }
      #pragma unroll
      for (int off = 32; off > 0; off >>= 1) {
        s0 += __shfl_down(s0, off);
        s1 += __shfl_down(s1, off);
        se += __shfl_down(se, off);
      }
      if (lane == 0) {
        out[YO + b * (Tn * 2) + (t - 1) * 2 + 0] = s0 + predb[0];
        out[YO + b * (Tn * 2) + (t - 1) * 2 + 1] = s1 + predb[1];
        out[EO + b * Tn + (t - 1)]               = se + enb[0];
      }
    }
    // x_t into hlstm ext cols (consumed by stage B after bar1)
    if (tid < Fn) {
      int b = rbase + wg;
      hls[b * KSn + 512 + tid] = f2bf(x[(b * Tn + t) * Fn + tid]);
    }

    // ---------- stage A: reg-pipelined stage h -> LDS; z = [h,x_t] @ Wh^T; gates ----------
    {
      u64 rg[17];
      #pragma unroll
      for (int i = 0; i < 17; ++i) {
        int idx = tid + i * 256;
        int r = idx / 136, ch = idx - r * 136;      // row = 544 shorts = 136 qwords
        rg[i] = ldq_agent((const char*)hsh + (rbase + r) * (KSn * 2) + ch * 8);
      }
      #pragma unroll
      for (int i = 0; i < 17; ++i) {
        int idx = tid + i * 256;
        int r = idx / 136, ch = idx - r * 136;
        *(u64*)(lds + LB_A + r * (KSP * 2) + ch * 8) = rg[i];
      }
    }
    __syncthreads();
    {
      f32x4 acc0 = {0.f, 0.f, 0.f, 0.f}, acc1 = {0.f, 0.f, 0.f, 0.f};
      const char* a0b = lds + LB_A + l15 * (KSP * 2) + l4 * 16;
      const char* a1b = a0b + 16 * (KSP * 2);
      const char* wb  = lds + LB_WH + (wv * 16 + l15) * (KSP * 2) + l4 * 16;
      #pragma unroll
      for (int ks = 0; ks < 17; ++ks) {
        bf16x8 a0 = *(const bf16x8*)(a0b + ks * 64);
        bf16x8 a1 = *(const bf16x8*)(a1b + ks * 64);
        bf16x8 b8 = *(const bf16x8*)(wb + ks * 64);
        acc0 = __builtin_amdgcn_mfma_f32_16x16x32_bf16(a0, b8, acc0, 0, 0, 0);
        acc1 = __builtin_amdgcn_mfma_f32_16x16x32_bf16(a1, b8, acc1, 0, 0, 0);
      }
      *(f32x4*)(&lbuf[wv][l15][l4 * 4])      = acc0;
      *(f32x4*)(&lbuf[wv][l15][16 + l4 * 4]) = acc1;
    }
    __syncthreads();
    {
      float zi0 = lbuf[0][cc][rr]      + biC[0];
      float zg0 = lbuf[1][cc][rr]      + biC[1];
      float zf0 = lbuf[2][cc][rr]      + biC[2];
      float zo0 = lbuf[3][cc][rr]      + biC[3];
      float zi1 = lbuf[0][cc][rr + 16] + biC[0];
      float zg1 = lbuf[1][cc][rr + 16] + biC[1];
      float zf1 = lbuf[2][cc][rr + 16] + biC[2];
      float zo1 = lbuf[3][cc][rr + 16] + biC[3];
      float cn0 = cst0 * sigm(zf0 + 1.f) + tanhx(zi0) * sigm(zg0);
      float cn1 = cst1 * sigm(zf1 + 1.f) + tanhx(zi1) * sigm(zg1);
      float hl0 = tanhx(cn0) * sigm(zo0);
      float hl1 = tanhx(cn1) * sigm(zo1);
      cst0 = cn0; cst1 = cn1;
      const int b0 = rbase + rr, b1 = rbase + rr + 16;
      hls[b0 * KSn + jbase + cc] = f2bf(hl0);
      hls[b1 * KSn + jbase + cc] = f2bf(hl1);
      if (t == Tn - 1) {
        out[CO + b0 * Hn + jbase + cc] = cn0;
        out[CO + b1 * Hn + jbase + cc] = cn1;
      }
    }
    ++phase; cluster_bar(cctr, phase * WPC, fastrun);

    // ---------- stage B: feat = lecun_tanh([h_lstm,x_t] @ bb^T) (WGs 0..7) ----------
    if (wg < 8) {
      {
        u64 rg[17];
        #pragma unroll
        for (int i = 0; i < 17; ++i) {
          int idx = tid + i * 256;
          int r = idx / 136, ch = idx - r * 136;
          rg[i] = ldq_agent((const char*)hls + (rbase + r) * (KSn * 2) + ch * 8);
        }
        #pragma unroll
        for (int i = 0; i < 17; ++i) {
          int idx = tid + i * 256;
          int r = idx / 136, ch = idx - r * 136;
          *(u64*)(lds + LB_A + r * (KSP * 2) + ch * 8) = rg[i];
        }
      }
      __syncthreads();
      if (wv < 2) {
        f32x4 accB = {0.f, 0.f, 0.f, 0.f};
        const char* ab = lds + LB_A + (wv * 16 + l15) * (KSP * 2) + l4 * 16;
        const unsigned short* brow = bbw + (wg * 16 + l15) * KSn + l4 * 8;
        #pragma unroll
        for (int ks = 0; ks < 17; ++ks) {
          bf16x8 a  = *(const bf16x8*)(ab + ks * 64);
          bf16x8 b8 = *(const bf16x8*)(brow + ks * 32);
          accB = __builtin_amdgcn_mfma_f32_16x16x32_bf16(a, b8, accB, 0, 0, 0);
        }
        #pragma unroll
        for (int j = 0; j < 4; ++j) {
          float v = accB[j] + bbB;
          v = 1.7159f * tanhx(0.666f * v);
          int b = rbase + wv * 16 + l4 * 4 + j;
          fsh[b * BBn + wg * 16 + l15] = f2bf(v);
        }
      }
    }
    ++phase; cluster_bar(cctr, phase * WPC, fastrun);

    // ---------- stage C: reg-pipelined stage feat -> LDS; ff1/ff2/ta/tb; h_new ----------
    {
      u64 rg[4];
      #pragma unroll
      for (int i = 0; i < 4; ++i) {
        int idx = tid + i * 256;
        int r = idx >> 5, ch = idx & 31;            // row = 128 shorts = 32 qwords
        rg[i] = ldq_agent((const char*)fsh + (rbase + r) * (BBn * 2) + ch * 8);
      }
      #pragma unroll
      for (int i = 0; i < 4; ++i) {
        int idx = tid + i * 256;
        int r = idx >> 5, ch = idx & 31;
        *(u64*)(lds + LB_A + r * (BBP * 2) + ch * 8) = rg[i];
      }
    }
    __syncthreads();
    {
      f32x4 ac0 = {0.f, 0.f, 0.f, 0.f}, ac1 = {0.f, 0.f, 0.f, 0.f};
      const char* a0b = lds + LB_A + l15 * (BBP * 2) + l4 * 16;
      const char* a1b = a0b + 16 * (BBP * 2);
      const char* wb  = lds + LB_FF + (wv * 16 + l15) * (BBP * 2) + l4 * 16;
      #pragma unroll
      for (int ks = 0; ks < 4; ++ks) {
        bf16x8 a0 = *(const bf16x8*)(a0b + ks * 64);
        bf16x8 a1 = *(const bf16x8*)(a1b + ks * 64);
        bf16x8 b8 = *(const bf16x8*)(wb + ks * 64);
        ac0 = __builtin_amdgcn_mfma_f32_16x16x32_bf16(a0, b8, ac0, 0, 0, 0);
        ac1 = __builtin_amdgcn_mfma_f32_16x16x32_bf16(a1, b8, ac1, 0, 0, 0);
      }
      *(f32x4*)(&lbuf[wv][l15][l4 * 4])      = ac0;
      *(f32x4*)(&lbuf[wv][l15][16 + l4 * 4]) = ac1;
    }
    __syncthreads();
    {
      float p10 = lbuf[0][cc][rr] + fb1,      p20 = lbuf[1][cc][rr] + fb2v;
      float pa0 = lbuf[2][cc][rr] + fta,      pb0 = lbuf[3][cc][rr] + ftb;
      float p11 = lbuf[0][cc][rr + 16] + fb1, p21 = lbuf[1][cc][rr + 16] + fb2v;
      float pa1 = lbuf[2][cc][rr + 16] + fta, pb1 = lbuf[3][cc][rr + 16] + ftb;
      float f10 = tanhx(p10), f20 = tanhx(p20), ti0 = sigm(pa0 + pb0);
      float f11 = tanhx(p11), f21 = tanhx(p21), ti1 = sigm(pa1 + pb1);
      float hn0 = f10 + ti0 * (f20 - f10);
      float hn1 = f11 + ti1 * (f21 - f11);
      const int b0 = rbase + rr, b1 = rbase + rr + 16;
      hsh[b0 * KSn + jbase + cc] = f2bf(hn0);
      hsh[b1 * KSn + jbase + cc] = f2bf(hn1);
      if (t == Tn - 1) {
        out[HO + b0 * Hn + jbase + cc] = hn0;
        out[HO + b1 * Hn + jbase + cc] = hn1;
      }
    }
    if (t + 1 < Tn && tid < Fn) {
      int b = rbase + wg;
      hsh[b * KSn + 512 + tid] = f2bf(x[(b * Tn + t + 1) * Fn + tid]);
    }
    ++phase; cluster_bar(cctr, phase * WPC, fastrun);
  }

  // ---------- epilogue heads for t = Tn-1 ----------
  if (wv == 0) {
    const int b = rbase + wg;
    u64 q0 = ldq_agent((const char*)hsh + b * (KSn * 2) + lane * 16);
    u64 q1 = ldq_agent((const char*)hsh + b * (KSn * 2) + lane * 16 + 8);
    float s0 = 0.f, s1 = 0.f, se = 0.f;
    #pragma unroll
    for (int j = 0; j < 8; ++j) {
      unsigned short us = (unsigned short)(((j < 4) ? q0 : q1) >> (16 * (j & 3)));
      float hv = bf2f(us);
      s0 += hv * hp0[j]; s1 += hv * hp1[j]; se += hv * hpe[j];
    }
    #pragma unroll
    for (int off = 32; off > 0; off >>= 1) {
      s0 += __shfl_down(s0, off);
      s1 += __shfl_down(s1, off);
      se += __shfl_down(se, off);
    }
    if (lane == 0) {
      out[YO + b * (Tn * 2) + (Tn - 1) * 2 + 0] = s0 + predb[0];
      out[YO + b * (Tn * 2) + (Tn - 1) * 2 + 1] = s1 + predb[1];
      out[EO + b * Tn + (Tn - 1)]               = se + enb[0];
    }
  }
}

extern "C" void kernel_launch(void* const* d_in, const int* in_sizes, int n_in,
                              void* d_out, int out_size, void* d_ws, size_t ws_size,
                              hipStream_t stream) {
  const float* x   = (const float*)d_in[0];
  const float* Wi  = (const float*)d_in[1];
  const float* bi  = (const float*)d_in[2];
  const float* Wh  = (const float*)d_in[3];
  const float* bbW = (const float*)d_in[4];
  const float* bbb = (const float*)d_in[5];
  const float* f1W = (const float*)d_in[6];
  const float* f1b = (const float*)d_in[7];
  const float* f2W = (const float*)d_in[8];
  const float* f2b = (const float*)d_in[9];
  const float* taW = (const float*)d_in[10];
  const float* tab = (const float*)d_in[11];
  const float* tbW = (const float*)d_in[12];
  const float* tbb = (const float*)d_in[13];
  const float* pW  = (const float*)d_in[14];
  const float* pb  = (const float*)d_in[15];
  const float* eW  = (const float*)d_in[16];
  const float* eb  = (const float*)d_in[17];
  float* out = (float*)d_out;
  char* ws = (char*)d_ws;

  static_assert(DYN_LDS == 123392, "LDS layout");
  (void)hipFuncSetAttribute((const void*)ebl_main,
                            hipFuncAttributeMaxDynamicSharedMemorySize, DYN_LDS);

  // zero barriers + verdict/probe tables + activation buffers (replayed every launch)
  hipMemsetAsync(ws, 0, WS_WH, stream);
  prep_weights<<<2048, 256, 0, stream>>>(Wh, Wi, bbW, f1W, f2W, taW, tbW, ws);

  void* args[] = { (void*)&x, (void*)&bi, (void*)&bbb, (void*)&f1b, (void*)&f2b,
                   (void*)&tab, (void*)&tbb, (void*)&pW, (void*)&pb, (void*)&eW,
                   (void*)&eb, (void*)&out, (void*)&ws };
  hipLaunchCooperativeKernel((const void*)ebl_main, dim3(NWG), dim3(256), args,
                             DYN_LDS, stream);
}